// Round 1
// baseline (4442.254 us; speedup 1.0000x reference)
//
#include <hip/hip_runtime.h>
#include <math.h>

#define NB   16      // batch
#define SEQL 197     // sequence length (196 patches + cls)
#define TB   (NB*SEQL)   // 3152 tokens
#define DIMM 256
#define DI   512
#define DS   16
#define NL   8

// ---------------- block-wide 2-value reduction (256 threads = 4 waves) -----
__device__ __forceinline__ void block_reduce_2(float& s1, float& s2, float* red, int tid){
  #pragma unroll
  for (int off = 32; off > 0; off >>= 1){
    s1 += __shfl_down(s1, off, 64);
    s2 += __shfl_down(s2, off, 64);
  }
  __syncthreads();                       // protect red across repeated calls
  if ((tid & 63) == 0){ red[(tid>>6)*2] = s1; red[(tid>>6)*2+1] = s2; }
  __syncthreads();
  s1 = red[0] + red[2] + red[4] + red[6];
  s2 = red[1] + red[3] + red[5] + red[7];
}

// ---------------- patch embed: gather + LN1 + (768x256 matvec) + LN2 + pos --
__global__ __launch_bounds__(256) void patch_embed(
    const float* __restrict__ img, const float* __restrict__ g1, const float* __restrict__ b1,
    const float* __restrict__ pe_w, const float* __restrict__ pe_b,
    const float* __restrict__ g2, const float* __restrict__ b2,
    const float* __restrict__ pos, float* __restrict__ x)
{
  __shared__ float xp[768];
  __shared__ float red[8];
  int blk = blockIdx.x;            // b*196 + patch
  int b = blk / 196, p = blk % 196;
  int hh = p / 14, ww = p % 14;
  int tid = threadIdx.x;

  float v[3]; float s = 0.f, s2 = 0.f;
  #pragma unroll
  for (int i = 0; i < 3; i++){
    int e  = tid + i*256;          // e = (p1*16+p2)*3 + c
    int c  = e % 3;
    int p2 = (e/3) % 16;
    int p1 = e / 48;
    float val = img[((b*3 + c)*224 + hh*16 + p1)*224 + ww*16 + p2];
    v[i] = val; s += val; s2 += val*val;
  }
  block_reduce_2(s, s2, red, tid);
  float mu = s * (1.f/768.f);
  float var = s2 * (1.f/768.f) - mu*mu;
  float rr = rsqrtf(var + 1e-5f);
  #pragma unroll
  for (int i = 0; i < 3; i++){
    int e = tid + i*256;
    xp[e] = (v[i] - mu) * rr * g1[e] + b1[e];
  }
  __syncthreads();

  float acc = pe_b[tid];
  #pragma unroll 8
  for (int k = 0; k < 768; k++)
    acc += xp[k] * pe_w[k*256 + tid];

  s = acc; s2 = acc*acc;
  block_reduce_2(s, s2, red, tid);
  mu = s * (1.f/256.f);
  var = s2 * (1.f/256.f) - mu*mu;
  rr = rsqrtf(var + 1e-5f);
  float o = (acc - mu) * rr * g2[tid] + b2[tid] + pos[(1+p)*256 + tid];
  x[((size_t)(b*SEQL + 1 + p))*256 + tid] = o;
}

// ---------------- cls token + pos[0] ---------------------------------------
__global__ __launch_bounds__(256) void cls_pos(
    const float* __restrict__ cls, const float* __restrict__ pos, float* __restrict__ x)
{
  int b = blockIdx.x, tid = threadIdx.x;
  x[(size_t)b*SEQL*256 + tid] = cls[tid] + pos[tid];
}

// ---------------- residual add + LayerNorm(256) ----------------------------
__global__ __launch_bounds__(256) void add_ln(
    const float* __restrict__ x, float* __restrict__ resid, float* __restrict__ xn,
    const float* __restrict__ g, const float* __restrict__ bta, int first)
{
  __shared__ float red[8];
  int t = blockIdx.x, tid = threadIdx.x;
  size_t idx = (size_t)t*256 + tid;
  float r = x[idx] + (first ? 0.f : resid[idx]);
  resid[idx] = r;
  float s = r, s2 = r*r;
  block_reduce_2(s, s2, red, tid);
  float mu = s * (1.f/256.f);
  float var = s2 * (1.f/256.f) - mu*mu;
  float rr = rsqrtf(var + 1e-5f);
  xn[idx] = (r - mu) * rr * g[tid] + bta[tid];
}

// ---------------- generic fp32 tiled GEMM: C = A[MxK] @ W[KxN] (+bias) -----
#define BM 64
#define BN 64
#define BK 16
__global__ __launch_bounds__(256) void gemm(
    const float* __restrict__ A, const float* __restrict__ W, const float* __restrict__ bias,
    float* __restrict__ C, int M, int N, int K)
{
  __shared__ float As[BK][BM+1];
  __shared__ float Ws[BK][BN+1];
  int bm = blockIdx.y * BM, bn = blockIdx.x * BN;
  int tid = threadIdx.x;
  int tx = tid & 15, ty = tid >> 4;       // 16x16 threads, each 4x4 outputs
  float acc[4][4] = {};

  for (int k0 = 0; k0 < K; k0 += BK){
    #pragma unroll
    for (int i = 0; i < 4; i++){
      int idx = tid + i*256;              // 0..1023
      int mm = idx >> 4, kk = idx & 15;
      int m = bm + mm;
      As[kk][mm] = (m < M) ? A[(size_t)m*K + k0 + kk] : 0.f;
    }
    #pragma unroll
    for (int i = 0; i < 4; i++){
      int idx = tid + i*256;
      int kk = idx >> 6, nn = idx & 63;
      int n = bn + nn;
      Ws[kk][nn] = (n < N) ? W[(size_t)(k0+kk)*N + n] : 0.f;
    }
    __syncthreads();
    #pragma unroll
    for (int kk = 0; kk < BK; kk++){
      float a[4], w[4];
      #pragma unroll
      for (int i = 0; i < 4; i++) a[i] = As[kk][ty*4+i];
      #pragma unroll
      for (int j = 0; j < 4; j++) w[j] = Ws[kk][tx*4+j];
      #pragma unroll
      for (int i = 0; i < 4; i++)
        #pragma unroll
        for (int j = 0; j < 4; j++)
          acc[i][j] += a[i]*w[j];
    }
    __syncthreads();
  }
  #pragma unroll
  for (int i = 0; i < 4; i++){
    int m = bm + ty*4 + i;
    if (m >= M) continue;
    #pragma unroll
    for (int j = 0; j < 4; j++){
      int n = bn + tx*4 + j;
      if (n >= N) continue;
      float v = acc[i][j] + (bias ? bias[n] : 0.f);
      C[(size_t)m*N + n] = v;
    }
  }
}

// ---------------- causal depthwise conv (k=4) + SiLU -----------------------
__global__ __launch_bounds__(256) void conv_silu(
    const float* __restrict__ xz, const float* __restrict__ cw, const float* __restrict__ cb,
    float* __restrict__ u)
{
  int gid = blockIdx.x*256 + threadIdx.x;
  if (gid >= TB*DI) return;
  int d = gid & 511;
  int t = gid >> 9;
  int l = t % SEQL;
  float acc = cb[d];
  if (l >= 3) acc += xz[(size_t)(t-3)*1024 + d] * cw[d*4+0];
  if (l >= 2) acc += xz[(size_t)(t-2)*1024 + d] * cw[d*4+1];
  if (l >= 1) acc += xz[(size_t)(t-1)*1024 + d] * cw[d*4+2];
  acc += xz[(size_t)t*1024 + d] * cw[d*4+3];
  float sg = 1.f / (1.f + expf(-acc));
  u[(size_t)t*512 + d] = acc * sg;
}

// ---------------- dt = softplus(dbc[:, :16] @ dtw + dtb) -------------------
__global__ __launch_bounds__(256) void dtproj_softplus(
    const float* __restrict__ dbc, const float* __restrict__ w, const float* __restrict__ bias,
    float* __restrict__ dt)
{
  __shared__ float row[16];
  int t = blockIdx.x, tid = threadIdx.x;
  if (tid < 16) row[tid] = dbc[(size_t)t*48 + tid];
  __syncthreads();
  for (int d = tid; d < 512; d += 256){
    float acc = bias[d];
    #pragma unroll
    for (int n = 0; n < 16; n++) acc += row[n] * w[n*512 + d];
    float sp = (acc > 20.f) ? acc : log1pf(expf(acc));
    dt[(size_t)t*512 + d] = sp;
  }
}

// ---------------- selective scan + Dp skip + SiLU(z) gate ------------------
__global__ __launch_bounds__(256) void scan_kernel(
    const float* __restrict__ dt, const float* __restrict__ u, const float* __restrict__ dbc,
    const float* __restrict__ xz, const float* __restrict__ A_log, const float* __restrict__ Dp,
    float* __restrict__ yg)
{
  int gid = blockIdx.x*256 + threadIdx.x;   // 0..8191
  int b = gid >> 9;
  int d = gid & 511;
  float A[DS], h[DS];
  #pragma unroll
  for (int n = 0; n < DS; n++){
    A[n] = -expf(A_log[d*DS + n]);
    h[n] = 0.f;
  }
  float dp = Dp[d];
  for (int l = 0; l < SEQL; l++){
    int t = b*SEQL + l;
    float dtv = dt[(size_t)t*512 + d];
    float uv  = u[(size_t)t*512 + d];
    float zv  = xz[(size_t)t*1024 + 512 + d];
    float dtu = dtv * uv;
    const float* bc = dbc + (size_t)t*48;
    float y = 0.f;
    #pragma unroll
    for (int n = 0; n < DS; n++){
      float hv = expf(dtv * A[n]) * h[n] + dtu * bc[16+n];
      h[n] = hv;
      y += hv * bc[32+n];
    }
    float sg = 1.f / (1.f + expf(-zv));
    yg[(size_t)t*512 + d] = (y + uv*dp) * zv * sg;
  }
}

// ---------------- final: resid add (token 0) + LN + head -------------------
__global__ __launch_bounds__(256) void final_head(
    const float* __restrict__ x, const float* __restrict__ resid,
    const float* __restrict__ g, const float* __restrict__ bta,
    const float* __restrict__ head_w, const float* __restrict__ head_b,
    float* __restrict__ out)
{
  __shared__ float xs[256];
  __shared__ float red[8];
  int b = blockIdx.x, tid = threadIdx.x;
  size_t idx = (size_t)b*SEQL*256 + tid;    // token 0 of batch b
  float r = x[idx] + resid[idx];
  float s = r, s2 = r*r;
  block_reduce_2(s, s2, red, tid);
  float mu = s * (1.f/256.f);
  float var = s2 * (1.f/256.f) - mu*mu;
  float rr = rsqrtf(var + 1e-5f);
  xs[tid] = (r - mu) * rr * g[tid] + bta[tid];
  __syncthreads();
  for (int j = tid; j < 1000; j += 256){
    float acc = head_b[j];
    #pragma unroll 8
    for (int k = 0; k < 256; k++) acc += xs[k] * head_w[k*1000 + j];
    out[(size_t)b*1000 + j] = acc;
  }
}

// ---------------------------------------------------------------------------
extern "C" void kernel_launch(void* const* d_in, const int* in_sizes, int n_in,
                              void* d_out, int out_size, void* d_ws, size_t ws_size,
                              hipStream_t stream) {
  const float* img   = (const float*)d_in[0];
  const float* ln1g  = (const float*)d_in[1];
  const float* ln1b  = (const float*)d_in[2];
  const float* pe_w  = (const float*)d_in[3];
  const float* pe_b  = (const float*)d_in[4];
  const float* ln2g  = (const float*)d_in[5];
  const float* ln2b  = (const float*)d_in[6];
  const float* pos   = (const float*)d_in[7];
  const float* cls   = (const float*)d_in[8];
  const float* ln_w  = (const float*)d_in[9];
  const float* ln_b  = (const float*)d_in[10];
  const float* in_w  = (const float*)d_in[11];
  const float* conv_w= (const float*)d_in[12];
  const float* conv_b= (const float*)d_in[13];
  const float* xproj = (const float*)d_in[14];
  const float* dtw   = (const float*)d_in[15];
  const float* dtb   = (const float*)d_in[16];
  const float* A_log = (const float*)d_in[17];
  const float* Dp    = (const float*)d_in[18];
  const float* out_w = (const float*)d_in[19];
  const float* nfw   = (const float*)d_in[20];
  const float* nfb   = (const float*)d_in[21];
  const float* head_w= (const float*)d_in[22];
  const float* head_b= (const float*)d_in[23];
  float* out = (float*)d_out;

  float* ws = (float*)d_ws;
  float* x     = ws;  ws += (size_t)TB*DIMM;
  float* resid = ws;  ws += (size_t)TB*DIMM;
  float* xn    = ws;  ws += (size_t)TB*DIMM;
  float* xz    = ws;  ws += (size_t)TB*2*DI;
  float* u     = ws;  ws += (size_t)TB*DI;
  float* dbc   = ws;  ws += (size_t)TB*48;
  float* dt    = ws;  ws += (size_t)TB*DI;
  float* yg    = ws;  ws += (size_t)TB*DI;

  patch_embed<<<dim3(NB*196), 256, 0, stream>>>(img, ln1g, ln1b, pe_w, pe_b, ln2g, ln2b, pos, x);
  cls_pos<<<NB, 256, 0, stream>>>(cls, pos, x);

  const int MT = (TB + BM - 1) / BM;   // 50
  for (int i = 0; i < NL; i++){
    add_ln<<<TB, 256, 0, stream>>>(x, resid, xn, ln_w + i*DIMM, ln_b + i*DIMM, i == 0 ? 1 : 0);
    gemm<<<dim3(1024/BN, MT), 256, 0, stream>>>(xn, in_w + (size_t)i*DIMM*1024, nullptr, xz, TB, 1024, DIMM);
    conv_silu<<<(TB*DI + 255)/256, 256, 0, stream>>>(xz, conv_w + i*DI*4, conv_b + i*DI, u);
    gemm<<<dim3(1, MT), 256, 0, stream>>>(u, xproj + i*DI*48, nullptr, dbc, TB, 48, DI);
    dtproj_softplus<<<TB, 256, 0, stream>>>(dbc, dtw + i*16*DI, dtb + i*DI, dt);
    scan_kernel<<<NB*DI/256, 256, 0, stream>>>(dt, u, dbc, xz, A_log + i*DI*DS, Dp + i*DI, yg);
    gemm<<<dim3(DIMM/BN, MT), 256, 0, stream>>>(yg, out_w + (size_t)i*DI*DIMM, nullptr, x, TB, DIMM, DI);
  }
  final_head<<<NB, 256, 0, stream>>>(x, resid, nfw, nfb, head_w, head_b, out);
}

// Round 2
// 3059.474 us; speedup vs baseline: 1.4520x; 1.4520x over previous
//
#include <hip/hip_runtime.h>
#include <math.h>

#define NB   16      // batch
#define SEQL 197     // sequence length (196 patches + cls)
#define TB   (NB*SEQL)   // 3152 tokens
#define DIMM 256
#define DI   512
#define DS   16
#define NL   8

// ---------------- block-wide 2-value reduction (256 threads = 4 waves) -----
__device__ __forceinline__ void block_reduce_2(float& s1, float& s2, float* red, int tid){
  #pragma unroll
  for (int off = 32; off > 0; off >>= 1){
    s1 += __shfl_down(s1, off, 64);
    s2 += __shfl_down(s2, off, 64);
  }
  __syncthreads();                       // protect red across repeated calls
  if ((tid & 63) == 0){ red[(tid>>6)*2] = s1; red[(tid>>6)*2+1] = s2; }
  __syncthreads();
  s1 = red[0] + red[2] + red[4] + red[6];
  s2 = red[1] + red[3] + red[5] + red[7];
}

// ---------------- patch embed: gather + LN1 + (768x256 matvec) + LN2 + pos --
__global__ __launch_bounds__(256) void patch_embed(
    const float* __restrict__ img, const float* __restrict__ g1, const float* __restrict__ b1,
    const float* __restrict__ pe_w, const float* __restrict__ pe_b,
    const float* __restrict__ g2, const float* __restrict__ b2,
    const float* __restrict__ pos, float* __restrict__ x)
{
  __shared__ float xp[768];
  __shared__ float red[8];
  int blk = blockIdx.x;            // b*196 + patch
  int b = blk / 196, p = blk % 196;
  int hh = p / 14, ww = p % 14;
  int tid = threadIdx.x;

  float v[3]; float s = 0.f, s2 = 0.f;
  #pragma unroll
  for (int i = 0; i < 3; i++){
    int e  = tid + i*256;          // e = (p1*16+p2)*3 + c
    int c  = e % 3;
    int p2 = (e/3) % 16;
    int p1 = e / 48;
    float val = img[((b*3 + c)*224 + hh*16 + p1)*224 + ww*16 + p2];
    v[i] = val; s += val; s2 += val*val;
  }
  block_reduce_2(s, s2, red, tid);
  float mu = s * (1.f/768.f);
  float var = s2 * (1.f/768.f) - mu*mu;
  float rr = rsqrtf(var + 1e-5f);
  #pragma unroll
  for (int i = 0; i < 3; i++){
    int e = tid + i*256;
    xp[e] = (v[i] - mu) * rr * g1[e] + b1[e];
  }
  __syncthreads();

  float acc = pe_b[tid];
  #pragma unroll 8
  for (int k = 0; k < 768; k++)
    acc += xp[k] * pe_w[k*256 + tid];

  s = acc; s2 = acc*acc;
  block_reduce_2(s, s2, red, tid);
  mu = s * (1.f/256.f);
  var = s2 * (1.f/256.f) - mu*mu;
  rr = rsqrtf(var + 1e-5f);
  float o = (acc - mu) * rr * g2[tid] + b2[tid] + pos[(1+p)*256 + tid];
  x[((size_t)(b*SEQL + 1 + p))*256 + tid] = o;
}

// ---------------- cls token + pos[0] ---------------------------------------
__global__ __launch_bounds__(256) void cls_pos(
    const float* __restrict__ cls, const float* __restrict__ pos, float* __restrict__ x)
{
  int b = blockIdx.x, tid = threadIdx.x;
  x[(size_t)b*SEQL*256 + tid] = cls[tid] + pos[tid];
}

// ---------------- residual add + LayerNorm(256) ----------------------------
__global__ __launch_bounds__(256) void add_ln(
    const float* __restrict__ x, float* __restrict__ resid, float* __restrict__ xn,
    const float* __restrict__ g, const float* __restrict__ bta, int first)
{
  __shared__ float red[8];
  int t = blockIdx.x, tid = threadIdx.x;
  size_t idx = (size_t)t*256 + tid;
  float r = x[idx] + (first ? 0.f : resid[idx]);
  resid[idx] = r;
  float s = r, s2 = r*r;
  block_reduce_2(s, s2, red, tid);
  float mu = s * (1.f/256.f);
  float var = s2 * (1.f/256.f) - mu*mu;
  float rr = rsqrtf(var + 1e-5f);
  xn[idx] = (r - mu) * rr * g[tid] + bta[tid];
}

// ---------------- generic fp32 tiled GEMM: C = A[MxK] @ W[KxN] (+bias) -----
// TX = BN/TN, TY = BM/TM, TX*TY must be 256.
template<int BM, int BN, int BK, int TM, int TN>
__global__ __launch_bounds__(256) void gemm_t(
    const float* __restrict__ A, const float* __restrict__ W, const float* __restrict__ bias,
    float* __restrict__ C, int M, int N, int K)
{
  __shared__ float As[BK][BM+4];   // +4 keeps 16B alignment for float4 reads
  __shared__ float Ws[BK][BN+4];
  constexpr int TX = BN / TN;
  constexpr int TY = BM / TM;
  static_assert(TX * TY == 256, "thread tile mismatch");
  int bm = blockIdx.y * BM, bn = blockIdx.x * BN;
  int tid = threadIdx.x;
  int tx = tid % TX, ty = tid / TX;
  float acc[TM][TN] = {};

  for (int k0 = 0; k0 < K; k0 += BK){
    #pragma unroll
    for (int idx = tid; idx < BM*BK; idx += 256){
      int mm = idx / BK, kk = idx % BK;
      int m = bm + mm;
      As[kk][mm] = (m < M) ? A[(size_t)m*K + k0 + kk] : 0.f;
    }
    #pragma unroll
    for (int idx = tid; idx < BK*BN; idx += 256){
      int kk = idx / BN, nn = idx % BN;
      int n = bn + nn;
      Ws[kk][nn] = (n < N) ? W[(size_t)(k0+kk)*N + n] : 0.f;
    }
    __syncthreads();
    #pragma unroll
    for (int kk = 0; kk < BK; kk++){
      float a[TM], w[TN];
      if constexpr (TM == 4){
        float4 av = *(const float4*)&As[kk][ty*TM];
        a[0]=av.x; a[1]=av.y; a[2]=av.z; a[3]=av.w;
      } else {
        #pragma unroll
        for (int i = 0; i < TM; i++) a[i] = As[kk][ty*TM+i];
      }
      if constexpr (TN == 4){
        float4 wv = *(const float4*)&Ws[kk][tx*TN];
        w[0]=wv.x; w[1]=wv.y; w[2]=wv.z; w[3]=wv.w;
      } else {
        #pragma unroll
        for (int j = 0; j < TN; j++) w[j] = Ws[kk][tx*TN+j];
      }
      #pragma unroll
      for (int i = 0; i < TM; i++)
        #pragma unroll
        for (int j = 0; j < TN; j++)
          acc[i][j] += a[i]*w[j];
    }
    __syncthreads();
  }
  #pragma unroll
  for (int i = 0; i < TM; i++){
    int m = bm + ty*TM + i;
    if (m >= M) continue;
    #pragma unroll
    for (int j = 0; j < TN; j++){
      int n = bn + tx*TN + j;
      if (n >= N) continue;
      float v = acc[i][j] + (bias ? bias[n] : 0.f);
      C[(size_t)m*N + n] = v;
    }
  }
}

// ---------------- causal depthwise conv (k=4) + SiLU -----------------------
__global__ __launch_bounds__(256) void conv_silu(
    const float* __restrict__ xz, const float* __restrict__ cw, const float* __restrict__ cb,
    float* __restrict__ u)
{
  int gid = blockIdx.x*256 + threadIdx.x;
  if (gid >= TB*DI) return;
  int d = gid & 511;
  int t = gid >> 9;
  int l = t % SEQL;
  float acc = cb[d];
  if (l >= 3) acc += xz[(size_t)(t-3)*1024 + d] * cw[d*4+0];
  if (l >= 2) acc += xz[(size_t)(t-2)*1024 + d] * cw[d*4+1];
  if (l >= 1) acc += xz[(size_t)(t-1)*1024 + d] * cw[d*4+2];
  acc += xz[(size_t)t*1024 + d] * cw[d*4+3];
  float sg = 1.f / (1.f + __expf(-acc));
  u[(size_t)t*512 + d] = acc * sg;
}

// ---------------- dt = softplus(dbc[:, :16] @ dtw + dtb) -------------------
__global__ __launch_bounds__(256) void dtproj_softplus(
    const float* __restrict__ dbc, const float* __restrict__ w, const float* __restrict__ bias,
    float* __restrict__ dt)
{
  __shared__ float row[16];
  int t = blockIdx.x, tid = threadIdx.x;
  if (tid < 16) row[tid] = dbc[(size_t)t*48 + tid];
  __syncthreads();
  for (int d = tid; d < 512; d += 256){
    float acc = bias[d];
    #pragma unroll
    for (int n = 0; n < 16; n++) acc += row[n] * w[n*512 + d];
    float sp = (acc > 20.f) ? acc : log1pf(expf(acc));
    dt[(size_t)t*512 + d] = sp;
  }
}

// ---------------- selective scan: 16 lanes per (b,d) chain, one per state n -
// h[n]_t evolves independently per n; y_t = sum_n h[n]C[n] via shfl_xor tree.
__global__ __launch_bounds__(256) void scan_kernel(
    const float* __restrict__ dt, const float* __restrict__ u, const float* __restrict__ dbc,
    const float* __restrict__ xz, const float* __restrict__ A_log, const float* __restrict__ Dp,
    float* __restrict__ yg)
{
  int gid = blockIdx.x*256 + threadIdx.x;   // 0..131071 = (b,d,n)
  int n = gid & 15;
  int d = (gid >> 4) & 511;
  int b = gid >> 13;
  float A = -__expf(A_log[d*DS + n]);
  float h = 0.f;
  float dp = Dp[d];
  const size_t base = (size_t)b * SEQL;
  for (int l = 0; l < SEQL; l++){
    size_t t = base + l;
    float dtv = dt[t*512 + d];          // broadcast across the 16 lanes
    float uv  = u[t*512 + d];
    float Bv  = dbc[t*48 + 16 + n];
    float Cv  = dbc[t*48 + 32 + n];
    h = __expf(dtv * A) * h + (dtv * uv) * Bv;
    float y = h * Cv;
    y += __shfl_xor(y, 1, 64);
    y += __shfl_xor(y, 2, 64);
    y += __shfl_xor(y, 4, 64);
    y += __shfl_xor(y, 8, 64);
    if (n == 0){
      float zv = xz[t*1024 + 512 + d];
      float sg = 1.f / (1.f + __expf(-zv));
      yg[t*512 + d] = (y + uv*dp) * zv * sg;
    }
  }
}

// ---------------- final: resid add (token 0) + LN + head -------------------
__global__ __launch_bounds__(256) void final_head(
    const float* __restrict__ x, const float* __restrict__ resid,
    const float* __restrict__ g, const float* __restrict__ bta,
    const float* __restrict__ head_w, const float* __restrict__ head_b,
    float* __restrict__ out)
{
  __shared__ float xs[256];
  __shared__ float red[8];
  int b = blockIdx.x, tid = threadIdx.x;
  size_t idx = (size_t)b*SEQL*256 + tid;    // token 0 of batch b
  float r = x[idx] + resid[idx];
  float s = r, s2 = r*r;
  block_reduce_2(s, s2, red, tid);
  float mu = s * (1.f/256.f);
  float var = s2 * (1.f/256.f) - mu*mu;
  float rr = rsqrtf(var + 1e-5f);
  xs[tid] = (r - mu) * rr * g[tid] + bta[tid];
  __syncthreads();
  for (int j = tid; j < 1000; j += 256){
    float acc = head_b[j];
    #pragma unroll 8
    for (int k = 0; k < 256; k++) acc += xs[k] * head_w[k*1000 + j];
    out[(size_t)b*1000 + j] = acc;
  }
}

// ---------------------------------------------------------------------------
extern "C" void kernel_launch(void* const* d_in, const int* in_sizes, int n_in,
                              void* d_out, int out_size, void* d_ws, size_t ws_size,
                              hipStream_t stream) {
  const float* img   = (const float*)d_in[0];
  const float* ln1g  = (const float*)d_in[1];
  const float* ln1b  = (const float*)d_in[2];
  const float* pe_w  = (const float*)d_in[3];
  const float* pe_b  = (const float*)d_in[4];
  const float* ln2g  = (const float*)d_in[5];
  const float* ln2b  = (const float*)d_in[6];
  const float* pos   = (const float*)d_in[7];
  const float* cls   = (const float*)d_in[8];
  const float* ln_w  = (const float*)d_in[9];
  const float* ln_b  = (const float*)d_in[10];
  const float* in_w  = (const float*)d_in[11];
  const float* conv_w= (const float*)d_in[12];
  const float* conv_b= (const float*)d_in[13];
  const float* xproj = (const float*)d_in[14];
  const float* dtw   = (const float*)d_in[15];
  const float* dtb   = (const float*)d_in[16];
  const float* A_log = (const float*)d_in[17];
  const float* Dp    = (const float*)d_in[18];
  const float* out_w = (const float*)d_in[19];
  const float* nfw   = (const float*)d_in[20];
  const float* nfb   = (const float*)d_in[21];
  const float* head_w= (const float*)d_in[22];
  const float* head_b= (const float*)d_in[23];
  float* out = (float*)d_out;

  float* ws = (float*)d_ws;
  float* x     = ws;  ws += (size_t)TB*DIMM;
  float* resid = ws;  ws += (size_t)TB*DIMM;
  float* xn    = ws;  ws += (size_t)TB*DIMM;
  float* xz    = ws;  ws += (size_t)TB*2*DI;
  float* u     = ws;  ws += (size_t)TB*DI;
  float* dbc   = ws;  ws += (size_t)TB*48;
  float* dt    = ws;  ws += (size_t)TB*DI;
  float* yg    = ws;  ws += (size_t)TB*DI;

  patch_embed<<<dim3(NB*196), 256, 0, stream>>>(img, ln1g, ln1b, pe_w, pe_b, ln2g, ln2b, pos, x);
  cls_pos<<<NB, 256, 0, stream>>>(cls, pos, x);

  const int MT = (TB + 63) / 64;   // 50
  for (int i = 0; i < NL; i++){
    add_ln<<<TB, 256, 0, stream>>>(x, resid, xn, ln_w + i*DIMM, ln_b + i*DIMM, i == 0 ? 1 : 0);
    gemm_t<64,64,16,4,4><<<dim3(1024/64, MT), 256, 0, stream>>>(
        xn, in_w + (size_t)i*DIMM*1024, nullptr, xz, TB, 1024, DIMM);
    conv_silu<<<(TB*DI + 255)/256, 256, 0, stream>>>(xz, conv_w + i*DI*4, conv_b + i*DI, u);
    gemm_t<64,16,32,4,1><<<dim3(3, MT), 256, 0, stream>>>(
        u, xproj + i*DI*48, nullptr, dbc, TB, 48, DI);
    dtproj_softplus<<<TB, 256, 0, stream>>>(dbc, dtw + i*16*DI, dtb + i*DI, dt);
    scan_kernel<<<NB*DI*DS/256, 256, 0, stream>>>(dt, u, dbc, xz, A_log + i*DI*DS, Dp + i*DI, yg);
    gemm_t<64,64,16,4,4><<<dim3(DIMM/64, MT), 256, 0, stream>>>(
        yg, out_w + (size_t)i*DI*DIMM, nullptr, x, TB, DIMM, DI);
  }
  final_head<<<NB, 256, 0, stream>>>(x, resid, nfw, nfb, head_w, head_b, out);
}

// Round 3
// 1714.149 us; speedup vs baseline: 2.5915x; 1.7848x over previous
//
#include <hip/hip_runtime.h>
#include <math.h>

#define NB   16      // batch
#define SEQL 197     // sequence length (196 patches + cls)
#define TB   (NB*SEQL)   // 3152 tokens
#define DIMM 256
#define DI   512
#define DS   16
#define NL   8

// ---------------- block-wide 2-value reduction (256 threads = 4 waves) -----
__device__ __forceinline__ void block_reduce_2(float& s1, float& s2, float* red, int tid){
  #pragma unroll
  for (int off = 32; off > 0; off >>= 1){
    s1 += __shfl_down(s1, off, 64);
    s2 += __shfl_down(s2, off, 64);
  }
  __syncthreads();                       // protect red across repeated calls
  if ((tid & 63) == 0){ red[(tid>>6)*2] = s1; red[(tid>>6)*2+1] = s2; }
  __syncthreads();
  s1 = red[0] + red[2] + red[4] + red[6];
  s2 = red[1] + red[3] + red[5] + red[7];
}

// ---------------- patch embed: gather + LN1 + (768x256 matvec) + LN2 + pos --
__global__ __launch_bounds__(256) void patch_embed(
    const float* __restrict__ img, const float* __restrict__ g1, const float* __restrict__ b1,
    const float* __restrict__ pe_w, const float* __restrict__ pe_b,
    const float* __restrict__ g2, const float* __restrict__ b2,
    const float* __restrict__ pos, float* __restrict__ x)
{
  __shared__ float xp[768];
  __shared__ float red[8];
  int blk = blockIdx.x;            // b*196 + patch
  int b = blk / 196, p = blk % 196;
  int hh = p / 14, ww = p % 14;
  int tid = threadIdx.x;

  float v[3]; float s = 0.f, s2 = 0.f;
  #pragma unroll
  for (int i = 0; i < 3; i++){
    int e  = tid + i*256;          // e = (p1*16+p2)*3 + c
    int c  = e % 3;
    int p2 = (e/3) % 16;
    int p1 = e / 48;
    float val = img[((b*3 + c)*224 + hh*16 + p1)*224 + ww*16 + p2];
    v[i] = val; s += val; s2 += val*val;
  }
  block_reduce_2(s, s2, red, tid);
  float mu = s * (1.f/768.f);
  float var = s2 * (1.f/768.f) - mu*mu;
  float rr = rsqrtf(var + 1e-5f);
  #pragma unroll
  for (int i = 0; i < 3; i++){
    int e = tid + i*256;
    xp[e] = (v[i] - mu) * rr * g1[e] + b1[e];
  }
  __syncthreads();

  float acc = pe_b[tid];
  #pragma unroll 8
  for (int k = 0; k < 768; k++)
    acc += xp[k] * pe_w[k*256 + tid];

  s = acc; s2 = acc*acc;
  block_reduce_2(s, s2, red, tid);
  mu = s * (1.f/256.f);
  var = s2 * (1.f/256.f) - mu*mu;
  rr = rsqrtf(var + 1e-5f);
  float o = (acc - mu) * rr * g2[tid] + b2[tid] + pos[(1+p)*256 + tid];
  x[((size_t)(b*SEQL + 1 + p))*256 + tid] = o;
}

// ---------------- cls token + pos[0] ---------------------------------------
__global__ __launch_bounds__(256) void cls_pos(
    const float* __restrict__ cls, const float* __restrict__ pos, float* __restrict__ x)
{
  int b = blockIdx.x, tid = threadIdx.x;
  x[(size_t)b*SEQL*256 + tid] = cls[tid] + pos[tid];
}

// ---------------- residual add + LayerNorm(256) ----------------------------
__global__ __launch_bounds__(256) void add_ln(
    const float* __restrict__ x, float* __restrict__ resid, float* __restrict__ xn,
    const float* __restrict__ g, const float* __restrict__ bta, int first)
{
  __shared__ float red[8];
  int t = blockIdx.x, tid = threadIdx.x;
  size_t idx = (size_t)t*256 + tid;
  float r = x[idx] + (first ? 0.f : resid[idx]);
  resid[idx] = r;
  float s = r, s2 = r*r;
  block_reduce_2(s, s2, red, tid);
  float mu = s * (1.f/256.f);
  float var = s2 * (1.f/256.f) - mu*mu;
  float rr = rsqrtf(var + 1e-5f);
  xn[idx] = (r - mu) * rr * g[tid] + bta[tid];
}

// ---------------- generic fp32 tiled GEMM: C = A[MxK] @ W[KxN] (+bias) -----
// float4-vectorized staging. Requires BK%4==0, BN%4==0, K%4==0, N%4==0.
template<int BM, int BN, int BK, int TM, int TN>
__global__ __launch_bounds__(256) void gemm_t(
    const float* __restrict__ A, const float* __restrict__ W, const float* __restrict__ bias,
    float* __restrict__ C, int M, int N, int K)
{
  __shared__ float As[BK][BM+4];   // (BM+4)*4B is 16B-multiple when BM%4==0
  __shared__ float Ws[BK][BN+4];
  constexpr int TX = BN / TN;
  constexpr int TY = BM / TM;
  static_assert(TX * TY == 256, "thread tile mismatch");
  int bm = blockIdx.y * BM, bn = blockIdx.x * BN;
  int tid = threadIdx.x;
  int tx = tid % TX, ty = tid / TX;
  float acc[TM][TN] = {};

  for (int k0 = 0; k0 < K; k0 += BK){
    // A tile: float4 along K, transpose into As
    #pragma unroll
    for (int f = tid; f < BM*(BK/4); f += 256){
      int mm = f / (BK/4), kq = f % (BK/4);
      int m = bm + mm;
      float4 v = make_float4(0.f,0.f,0.f,0.f);
      if (m < M) v = *(const float4*)&A[(size_t)m*K + k0 + kq*4];
      As[kq*4+0][mm]=v.x; As[kq*4+1][mm]=v.y; As[kq*4+2][mm]=v.z; As[kq*4+3][mm]=v.w;
    }
    // W tile: float4 along N
    #pragma unroll
    for (int f = tid; f < BK*(BN/4); f += 256){
      int kk = f / (BN/4), nq = f % (BN/4);
      int n = bn + nq*4;
      if (n + 4 <= N){
        *(float4*)&Ws[kk][nq*4] = *(const float4*)&W[(size_t)(k0+kk)*N + n];
      } else {
        #pragma unroll
        for (int j = 0; j < 4; j++)
          Ws[kk][nq*4+j] = (n+j < N) ? W[(size_t)(k0+kk)*N + n + j] : 0.f;
      }
    }
    __syncthreads();
    #pragma unroll
    for (int kk = 0; kk < BK; kk++){
      float a[TM], w[TN];
      if constexpr (TM % 4 == 0){
        #pragma unroll
        for (int i = 0; i < TM; i += 4){
          float4 av = *(const float4*)&As[kk][ty*TM+i];
          a[i]=av.x; a[i+1]=av.y; a[i+2]=av.z; a[i+3]=av.w;
        }
      } else {
        #pragma unroll
        for (int i = 0; i < TM; i++) a[i] = As[kk][ty*TM+i];
      }
      if constexpr (TN % 4 == 0){
        #pragma unroll
        for (int j = 0; j < TN; j += 4){
          float4 wv = *(const float4*)&Ws[kk][tx*TN+j];
          w[j]=wv.x; w[j+1]=wv.y; w[j+2]=wv.z; w[j+3]=wv.w;
        }
      } else {
        #pragma unroll
        for (int j = 0; j < TN; j++) w[j] = Ws[kk][tx*TN+j];
      }
      #pragma unroll
      for (int i = 0; i < TM; i++)
        #pragma unroll
        for (int j = 0; j < TN; j++)
          acc[i][j] += a[i]*w[j];
    }
    __syncthreads();
  }
  #pragma unroll
  for (int i = 0; i < TM; i++){
    int m = bm + ty*TM + i;
    if (m >= M) continue;
    #pragma unroll
    for (int j = 0; j < TN; j++){
      int n = bn + tx*TN + j;
      if (n >= N) continue;
      float v = acc[i][j] + (bias ? bias[n] : 0.f);
      C[(size_t)m*N + n] = v;
    }
  }
}

// ---------------- causal depthwise conv (k=4) + SiLU -----------------------
__global__ __launch_bounds__(256) void conv_silu(
    const float* __restrict__ xz, const float* __restrict__ cw, const float* __restrict__ cb,
    float* __restrict__ u)
{
  int gid = blockIdx.x*256 + threadIdx.x;
  if (gid >= TB*DI) return;
  int d = gid & 511;
  int t = gid >> 9;
  int l = t % SEQL;
  float acc = cb[d];
  if (l >= 3) acc += xz[(size_t)(t-3)*1024 + d] * cw[d*4+0];
  if (l >= 2) acc += xz[(size_t)(t-2)*1024 + d] * cw[d*4+1];
  if (l >= 1) acc += xz[(size_t)(t-1)*1024 + d] * cw[d*4+2];
  acc += xz[(size_t)t*1024 + d] * cw[d*4+3];
  float sg = 1.f / (1.f + __expf(-acc));
  u[(size_t)t*512 + d] = acc * sg;
}

// ---------------- dt = softplus(dbc[:, :16] @ dtw + dtb), 8 tokens/block ---
__global__ __launch_bounds__(256) void dtproj_softplus(
    const float* __restrict__ dbc, const float* __restrict__ w, const float* __restrict__ bias,
    float* __restrict__ dt)
{
  __shared__ float row[8][16];
  int t0 = blockIdx.x*8, tid = threadIdx.x;
  if (tid < 128) row[tid>>4][tid&15] = dbc[(size_t)(t0 + (tid>>4))*48 + (tid&15)];
  __syncthreads();
  #pragma unroll
  for (int d = tid; d < 512; d += 256){
    float wc[16];
    #pragma unroll
    for (int n = 0; n < 16; n++) wc[n] = w[n*512 + d];
    float bv = bias[d];
    #pragma unroll
    for (int tt = 0; tt < 8; tt++){
      float acc = bv;
      #pragma unroll
      for (int n = 0; n < 16; n++) acc += row[tt][n] * wc[n];
      float sp = (acc > 20.f) ? acc : log1pf(__expf(acc));
      dt[(size_t)(t0+tt)*512 + d] = sp;
    }
  }
}

// ---------------- selective scan: LDS-staged, double-buffered chunks -------
// Block = (b, group of 16 d). thread = dl*16 + n (16 states per chain,
// chain = 16 consecutive lanes -> shfl_xor 1/2/4/8 reduces over n).
#define SCT 32                       // timesteps per chunk
#define NCH ((SEQL + SCT - 1)/SCT)   // 7
__global__ __launch_bounds__(256) void scan_kernel(
    const float* __restrict__ dt, const float* __restrict__ u, const float* __restrict__ dbc,
    const float* __restrict__ xz, const float* __restrict__ A_log, const float* __restrict__ Dp,
    float* __restrict__ yg)
{
  __shared__ float s_dt[2][SCT][16];
  __shared__ float s_u [2][SCT][16];
  __shared__ float s_z [2][SCT][16];
  __shared__ float s_bc[2][SCT][32];   // [..][n]=B, [..][16+n]=C
  __shared__ float s_y [2][SCT][16];

  int tid = threadIdx.x;
  int n = tid & 15, dl = tid >> 4;
  int b = blockIdx.x >> 5, dg = blockIdx.x & 31;
  int d0 = dg * 16;
  int d  = d0 + dl;
  const size_t base = (size_t)b * SEQL;

  float A = -__expf(A_log[d*DS + n]);
  float h = 0.f;
  float dp = Dp[d];

  // per-thread cooperative-load coordinates
  // dt/u/z: v = tid + i*256 (i=0,1): tl = v>>4, j = v&15
  // bc:     v = tid + i*256 (i=0..3): tl = v>>5, j = v&31
  float r_dt[2], r_u[2], r_z[2], r_bc[4];

  auto load_regs = [&](int c){
    #pragma unroll
    for (int i = 0; i < 2; i++){
      int v = tid + i*256;
      int tg = c*SCT + (v>>4); if (tg > SEQL-1) tg = SEQL-1;
      size_t t = base + tg;
      r_dt[i] = dt[t*512 + d0 + (v&15)];
      r_u [i] = u [t*512 + d0 + (v&15)];
      r_z [i] = xz[t*1024 + 512 + d0 + (v&15)];
    }
    #pragma unroll
    for (int i = 0; i < 4; i++){
      int v = tid + i*256;
      int tg = c*SCT + (v>>5); if (tg > SEQL-1) tg = SEQL-1;
      r_bc[i] = dbc[(base + tg)*48 + 16 + (v&31)];
    }
  };
  auto write_lds = [&](int buf){
    #pragma unroll
    for (int i = 0; i < 2; i++){
      int v = tid + i*256;
      s_dt[buf][v>>4][v&15] = r_dt[i];
      s_u [buf][v>>4][v&15] = r_u[i];
      s_z [buf][v>>4][v&15] = r_z[i];
    }
    #pragma unroll
    for (int i = 0; i < 4; i++){
      int v = tid + i*256;
      s_bc[buf][v>>5][v&31] = r_bc[i];
    }
  };

  load_regs(0);
  write_lds(0);
  __syncthreads();

  for (int c = 0; c < NCH; c++){
    int cur = c & 1;
    if (c + 1 < NCH) load_regs(c+1);          // prefetch (in flight during compute)

    int steps = SEQL - c*SCT; if (steps > SCT) steps = SCT;
    for (int tl = 0; tl < steps; tl++){
      float dtv = s_dt[cur][tl][dl];
      float uv  = s_u [cur][tl][dl];
      float Bv  = s_bc[cur][tl][n];
      float Cv  = s_bc[cur][tl][16+n];
      h = __expf(dtv * A) * h + (dtv * uv) * Bv;
      float y = h * Cv;
      y += __shfl_xor(y, 1, 64);
      y += __shfl_xor(y, 2, 64);
      y += __shfl_xor(y, 4, 64);
      y += __shfl_xor(y, 8, 64);
      if (n == 0){
        float zv = s_z[cur][tl][dl];
        float sg = 1.f / (1.f + __expf(-zv));
        s_y[cur][tl][dl] = (y + uv*dp) * zv * sg;
      }
    }
    __syncthreads();                           // all reads of buf cur + s_y writes done
    if (c + 1 < NCH) write_lds(1 - cur);       // fill next buffer
    // coalesced y store for chunk c
    #pragma unroll
    for (int i = 0; i < 2; i++){
      int v = tid + i*256;
      int tl = v >> 4, tg = c*SCT + tl;
      if (tg < SEQL)
        yg[(base + tg)*512 + d0 + (v&15)] = s_y[cur][tl][v&15];
    }
    __syncthreads();                           // next buffer complete
  }
}

// ---------------- final: resid add (token 0) + LN + head -------------------
__global__ __launch_bounds__(256) void final_head(
    const float* __restrict__ x, const float* __restrict__ resid,
    const float* __restrict__ g, const float* __restrict__ bta,
    const float* __restrict__ head_w, const float* __restrict__ head_b,
    float* __restrict__ out)
{
  __shared__ float xs[256];
  __shared__ float red[8];
  int b = blockIdx.x, tid = threadIdx.x;
  size_t idx = (size_t)b*SEQL*256 + tid;    // token 0 of batch b
  float r = x[idx] + resid[idx];
  float s = r, s2 = r*r;
  block_reduce_2(s, s2, red, tid);
  float mu = s * (1.f/256.f);
  float var = s2 * (1.f/256.f) - mu*mu;
  float rr = rsqrtf(var + 1e-5f);
  xs[tid] = (r - mu) * rr * g[tid] + bta[tid];
  __syncthreads();
  for (int j = tid; j < 1000; j += 256){
    float acc = head_b[j];
    #pragma unroll 8
    for (int k = 0; k < 256; k++) acc += xs[k] * head_w[k*1000 + j];
    out[(size_t)b*1000 + j] = acc;
  }
}

// ---------------------------------------------------------------------------
extern "C" void kernel_launch(void* const* d_in, const int* in_sizes, int n_in,
                              void* d_out, int out_size, void* d_ws, size_t ws_size,
                              hipStream_t stream) {
  const float* img   = (const float*)d_in[0];
  const float* ln1g  = (const float*)d_in[1];
  const float* ln1b  = (const float*)d_in[2];
  const float* pe_w  = (const float*)d_in[3];
  const float* pe_b  = (const float*)d_in[4];
  const float* ln2g  = (const float*)d_in[5];
  const float* ln2b  = (const float*)d_in[6];
  const float* pos   = (const float*)d_in[7];
  const float* cls   = (const float*)d_in[8];
  const float* ln_w  = (const float*)d_in[9];
  const float* ln_b  = (const float*)d_in[10];
  const float* in_w  = (const float*)d_in[11];
  const float* conv_w= (const float*)d_in[12];
  const float* conv_b= (const float*)d_in[13];
  const float* xproj = (const float*)d_in[14];
  const float* dtw   = (const float*)d_in[15];
  const float* dtb   = (const float*)d_in[16];
  const float* A_log = (const float*)d_in[17];
  const float* Dp    = (const float*)d_in[18];
  const float* out_w = (const float*)d_in[19];
  const float* nfw   = (const float*)d_in[20];
  const float* nfb   = (const float*)d_in[21];
  const float* head_w= (const float*)d_in[22];
  const float* head_b= (const float*)d_in[23];
  float* out = (float*)d_out;

  float* ws = (float*)d_ws;
  float* x     = ws;  ws += (size_t)TB*DIMM;
  float* resid = ws;  ws += (size_t)TB*DIMM;
  float* xn    = ws;  ws += (size_t)TB*DIMM;
  float* xz    = ws;  ws += (size_t)TB*2*DI;
  float* u     = ws;  ws += (size_t)TB*DI;
  float* dbc   = ws;  ws += (size_t)TB*48;
  float* dt    = ws;  ws += (size_t)TB*DI;
  float* yg    = ws;  ws += (size_t)TB*DI;

  patch_embed<<<dim3(NB*196), 256, 0, stream>>>(img, ln1g, ln1b, pe_w, pe_b, ln2g, ln2b, pos, x);
  cls_pos<<<NB, 256, 0, stream>>>(cls, pos, x);

  for (int i = 0; i < NL; i++){
    add_ln<<<TB, 256, 0, stream>>>(x, resid, xn, ln_w + i*DIMM, ln_b + i*DIMM, i == 0 ? 1 : 0);
    gemm_t<128,64,16,8,4><<<dim3(1024/64, (TB+127)/128), 256, 0, stream>>>(
        xn, in_w + (size_t)i*DIMM*1024, nullptr, xz, TB, 1024, DIMM);
    conv_silu<<<(TB*DI + 255)/256, 256, 0, stream>>>(xz, conv_w + i*DI*4, conv_b + i*DI, u);
    gemm_t<64,16,32,4,1><<<dim3(3, (TB+63)/64), 256, 0, stream>>>(
        u, xproj + i*DI*48, nullptr, dbc, TB, 48, DI);
    dtproj_softplus<<<TB/8, 256, 0, stream>>>(dbc, dtw + i*16*DI, dtb + i*DI, dt);
    scan_kernel<<<NB*32, 256, 0, stream>>>(dt, u, dbc, xz, A_log + i*DI*DS, Dp + i*DI, yg);
    gemm_t<64,64,16,4,4><<<dim3(DIMM/64, (TB+63)/64), 256, 0, stream>>>(
        yg, out_w + (size_t)i*DI*DIMM, nullptr, x, TB, DIMM, DI);
  }
  final_head<<<NB, 256, 0, stream>>>(x, resid, nfw, nfb, head_w, head_b, out);
}

// Round 4
// 1253.741 us; speedup vs baseline: 3.5432x; 1.3672x over previous
//
#include <hip/hip_runtime.h>
#include <math.h>

#define NB   16      // batch
#define SEQL 197     // sequence length (196 patches + cls)
#define TB   (NB*SEQL)   // 3152 tokens
#define DIMM 256
#define DI   512
#define DS   16
#define NL   8

typedef __bf16 bf16x8 __attribute__((ext_vector_type(8)));
typedef float floatx4 __attribute__((ext_vector_type(4)));

// ---------------- block-wide 2-value reduction (256 threads = 4 waves) -----
__device__ __forceinline__ void block_reduce_2(float& s1, float& s2, float* red, int tid){
  #pragma unroll
  for (int off = 32; off > 0; off >>= 1){
    s1 += __shfl_down(s1, off, 64);
    s2 += __shfl_down(s2, off, 64);
  }
  __syncthreads();
  if ((tid & 63) == 0){ red[(tid>>6)*2] = s1; red[(tid>>6)*2+1] = s2; }
  __syncthreads();
  s1 = red[0] + red[2] + red[4] + red[6];
  s2 = red[1] + red[3] + red[5] + red[7];
}

// ---------------- weight cast+transpose: in[K][N] fp32 -> out[N][K] bf16 ---
__global__ __launch_bounds__(256) void transpose_bf16(
    const float* __restrict__ in, __bf16* __restrict__ out, int K, int N)
{
  __shared__ float t[32][33];
  const float* src = in  + (size_t)blockIdx.z*K*N;
  __bf16*      dst = out + (size_t)blockIdx.z*K*N;
  int n0 = blockIdx.x*32, k0 = blockIdx.y*32;
  int tx = threadIdx.x & 31, ty = threadIdx.x >> 5;   // 32 x 8
  #pragma unroll
  for (int j = 0; j < 4; j++)
    t[ty + j*8][tx] = src[(size_t)(k0 + ty + j*8)*N + n0 + tx];
  __syncthreads();
  #pragma unroll
  for (int j = 0; j < 4; j++)
    dst[(size_t)(n0 + ty + j*8)*K + k0 + tx] = (__bf16)t[tx][ty + j*8];
}

// ---------------- bf16 MFMA GEMM: C fp32 = A[M][K] @ Wt[N][K]^T (+bias) ----
// 256 threads = 4 waves in 2x2; wave tile (BM/2)x(BN/2); 16x16x32 mfma.
template<int BM, int BN>
__global__ __launch_bounds__(256) void gemm_bf16(
    const __bf16* __restrict__ A, const __bf16* __restrict__ Wt,
    const float* __restrict__ bias, float* __restrict__ C, int M, int N, int K)
{
  constexpr int BK  = 32;
  constexpr int LDA = BK + 8;            // 40 elems = 80 B rows (16B-aligned, ~2-way banks)
  constexpr int TMW = BM/32;             // 16-row mfma tiles per wave
  constexpr int TNW = BN/32;
  __shared__ __bf16 As[BM][LDA];
  __shared__ __bf16 Bs[BN][LDA];

  int tid  = threadIdx.x;
  int lane = tid & 63, w = tid >> 6;
  int wm = w >> 1, wn = w & 1;
  int l15 = lane & 15, quad = lane >> 4;
  int bm = blockIdx.y * BM, bn = blockIdx.x * BN;

  floatx4 acc[TMW][TNW] = {};

  for (int k0 = 0; k0 < K; k0 += BK){
    // stage A: BM rows x 32 k (64B/row = 4 x 16B chunks)
    #pragma unroll
    for (int i = 0; i < BM/64; i++){
      int c = tid + i*256;
      int row = c >> 2, kc = c & 3;
      int m = bm + row;
      uint4 v = make_uint4(0,0,0,0);
      if (m < M) v = ((const uint4*)(A + (size_t)m*K + k0))[kc];
      *(uint4*)&As[row][kc*8] = v;
    }
    // stage B: BN rows(n) x 32 k
    #pragma unroll
    for (int i = 0; i < BN/64; i++){
      int c = tid + i*256;
      int row = c >> 2, kc = c & 3;
      int n = bn + row;
      uint4 v = ((const uint4*)(Wt + (size_t)n*K + k0))[kc];
      *(uint4*)&Bs[row][kc*8] = v;
    }
    __syncthreads();
    bf16x8 af[TMW], bf[TNW];
    #pragma unroll
    for (int mi = 0; mi < TMW; mi++)
      af[mi] = *(const bf16x8*)&As[wm*(BM/2) + mi*16 + l15][quad*8];
    #pragma unroll
    for (int ni = 0; ni < TNW; ni++)
      bf[ni] = *(const bf16x8*)&Bs[wn*(BN/2) + ni*16 + l15][quad*8];
    #pragma unroll
    for (int mi = 0; mi < TMW; mi++)
      #pragma unroll
      for (int ni = 0; ni < TNW; ni++)
        acc[mi][ni] = __builtin_amdgcn_mfma_f32_16x16x32_bf16(af[mi], bf[ni], acc[mi][ni], 0, 0, 0);
    __syncthreads();
  }
  // store: D col=lane&15, row=quad*4+reg
  #pragma unroll
  for (int mi = 0; mi < TMW; mi++){
    #pragma unroll
    for (int ni = 0; ni < TNW; ni++){
      int col = bn + wn*(BN/2) + ni*16 + l15;
      float bv = bias ? bias[col] : 0.f;
      #pragma unroll
      for (int r = 0; r < 4; r++){
        int row = bm + wm*(BM/2) + mi*16 + quad*4 + r;
        if (row < M) C[(size_t)row*N + col] = acc[mi][ni][r] + bv;
      }
    }
  }
}

// ---------------- patch LN1: gather + LayerNorm(768) -> bf16 ---------------
__global__ __launch_bounds__(256) void patch_ln1(
    const float* __restrict__ img, const float* __restrict__ g1, const float* __restrict__ b1,
    __bf16* __restrict__ xp_bf)
{
  __shared__ float red[8];
  int blk = blockIdx.x;            // b*196 + patch
  int b = blk / 196, p = blk % 196;
  int hh = p / 14, ww = p % 14;
  int tid = threadIdx.x;

  float v[3]; float s = 0.f, s2 = 0.f;
  #pragma unroll
  for (int i = 0; i < 3; i++){
    int e  = tid + i*256;          // e = (p1*16+p2)*3 + c
    int c  = e % 3;
    int p2 = (e/3) % 16;
    int p1 = e / 48;
    float val = img[((b*3 + c)*224 + hh*16 + p1)*224 + ww*16 + p2];
    v[i] = val; s += val; s2 += val*val;
  }
  block_reduce_2(s, s2, red, tid);
  float mu = s * (1.f/768.f);
  float var = s2 * (1.f/768.f) - mu*mu;
  float rr = rsqrtf(var + 1e-5f);
  #pragma unroll
  for (int i = 0; i < 3; i++){
    int e = tid + i*256;
    xp_bf[(size_t)blk*768 + e] = (__bf16)((v[i] - mu) * rr * g1[e] + b1[e]);
  }
}

// ---------------- patch LN2 + pos ------------------------------------------
__global__ __launch_bounds__(256) void ln2_pos(
    const float* __restrict__ pemb, const float* __restrict__ g2, const float* __restrict__ b2,
    const float* __restrict__ pos, float* __restrict__ x)
{
  __shared__ float red[8];
  int blk = blockIdx.x;
  int b = blk / 196, p = blk % 196;
  int tid = threadIdx.x;
  float v = pemb[(size_t)blk*256 + tid];
  float s = v, s2 = v*v;
  block_reduce_2(s, s2, red, tid);
  float mu = s * (1.f/256.f);
  float var = s2 * (1.f/256.f) - mu*mu;
  float rr = rsqrtf(var + 1e-5f);
  float o = (v - mu) * rr * g2[tid] + b2[tid] + pos[(1+p)*256 + tid];
  x[((size_t)(b*SEQL + 1 + p))*256 + tid] = o;
}

// ---------------- cls token + pos[0] ---------------------------------------
__global__ __launch_bounds__(256) void cls_pos(
    const float* __restrict__ cls, const float* __restrict__ pos, float* __restrict__ x)
{
  int b = blockIdx.x, tid = threadIdx.x;
  x[(size_t)b*SEQL*256 + tid] = cls[tid] + pos[tid];
}

// ---------------- residual add + LayerNorm(256) -> bf16 --------------------
__global__ __launch_bounds__(256) void add_ln(
    const float* __restrict__ x, float* __restrict__ resid, __bf16* __restrict__ xn_bf,
    const float* __restrict__ g, const float* __restrict__ bta, int first)
{
  __shared__ float red[8];
  int t = blockIdx.x, tid = threadIdx.x;
  size_t idx = (size_t)t*256 + tid;
  float r = x[idx] + (first ? 0.f : resid[idx]);
  resid[idx] = r;
  float s = r, s2 = r*r;
  block_reduce_2(s, s2, red, tid);
  float mu = s * (1.f/256.f);
  float var = s2 * (1.f/256.f) - mu*mu;
  float rr = rsqrtf(var + 1e-5f);
  xn_bf[idx] = (__bf16)((r - mu) * rr * g[tid] + bta[tid]);
}

// ---------------- generic fp32 tiled GEMM (used for xproj N=48) ------------
template<int BM, int BN, int BK, int TM, int TN>
__global__ __launch_bounds__(256) void gemm_t(
    const float* __restrict__ A, const float* __restrict__ W, const float* __restrict__ bias,
    float* __restrict__ C, int M, int N, int K)
{
  __shared__ float As[BK][BM+4];
  __shared__ float Ws[BK][BN+4];
  constexpr int TX = BN / TN;
  constexpr int TY = BM / TM;
  static_assert(TX * TY == 256, "thread tile mismatch");
  int bm = blockIdx.y * BM, bn = blockIdx.x * BN;
  int tid = threadIdx.x;
  int tx = tid % TX, ty = tid / TX;
  float acc[TM][TN] = {};

  for (int k0 = 0; k0 < K; k0 += BK){
    #pragma unroll
    for (int f = tid; f < BM*(BK/4); f += 256){
      int mm = f / (BK/4), kq = f % (BK/4);
      int m = bm + mm;
      float4 v = make_float4(0.f,0.f,0.f,0.f);
      if (m < M) v = *(const float4*)&A[(size_t)m*K + k0 + kq*4];
      As[kq*4+0][mm]=v.x; As[kq*4+1][mm]=v.y; As[kq*4+2][mm]=v.z; As[kq*4+3][mm]=v.w;
    }
    #pragma unroll
    for (int f = tid; f < BK*(BN/4); f += 256){
      int kk = f / (BN/4), nq = f % (BN/4);
      int n = bn + nq*4;
      if (n + 4 <= N){
        *(float4*)&Ws[kk][nq*4] = *(const float4*)&W[(size_t)(k0+kk)*N + n];
      } else {
        #pragma unroll
        for (int j = 0; j < 4; j++)
          Ws[kk][nq*4+j] = (n+j < N) ? W[(size_t)(k0+kk)*N + n + j] : 0.f;
      }
    }
    __syncthreads();
    #pragma unroll
    for (int kk = 0; kk < BK; kk++){
      float a[TM], w[TN];
      #pragma unroll
      for (int i = 0; i < TM; i++) a[i] = As[kk][ty*TM+i];
      #pragma unroll
      for (int j = 0; j < TN; j++) w[j] = Ws[kk][tx*TN+j];
      #pragma unroll
      for (int i = 0; i < TM; i++)
        #pragma unroll
        for (int j = 0; j < TN; j++)
          acc[i][j] += a[i]*w[j];
    }
    __syncthreads();
  }
  #pragma unroll
  for (int i = 0; i < TM; i++){
    int m = bm + ty*TM + i;
    if (m >= M) continue;
    #pragma unroll
    for (int j = 0; j < TN; j++){
      int n = bn + tx*TN + j;
      if (n >= N) continue;
      float v = acc[i][j] + (bias ? bias[n] : 0.f);
      C[(size_t)m*N + n] = v;
    }
  }
}

// ---------------- causal depthwise conv (k=4) + SiLU -----------------------
__global__ __launch_bounds__(256) void conv_silu(
    const float* __restrict__ xz, const float* __restrict__ cw, const float* __restrict__ cb,
    float* __restrict__ u)
{
  int gid = blockIdx.x*256 + threadIdx.x;
  if (gid >= TB*DI) return;
  int d = gid & 511;
  int t = gid >> 9;
  int l = t % SEQL;
  float acc = cb[d];
  if (l >= 3) acc += xz[(size_t)(t-3)*1024 + d] * cw[d*4+0];
  if (l >= 2) acc += xz[(size_t)(t-2)*1024 + d] * cw[d*4+1];
  if (l >= 1) acc += xz[(size_t)(t-1)*1024 + d] * cw[d*4+2];
  acc += xz[(size_t)t*1024 + d] * cw[d*4+3];
  float sg = 1.f / (1.f + __expf(-acc));
  u[(size_t)t*512 + d] = acc * sg;
}

// ---------------- dt = softplus(dbc[:, :16] @ dtw + dtb), 8 tokens/block ---
__global__ __launch_bounds__(256) void dtproj_softplus(
    const float* __restrict__ dbc, const float* __restrict__ w, const float* __restrict__ bias,
    float* __restrict__ dt)
{
  __shared__ float row[8][16];
  int t0 = blockIdx.x*8, tid = threadIdx.x;
  if (tid < 128) row[tid>>4][tid&15] = dbc[(size_t)(t0 + (tid>>4))*48 + (tid&15)];
  __syncthreads();
  #pragma unroll
  for (int d = tid; d < 512; d += 256){
    float wc[16];
    #pragma unroll
    for (int n = 0; n < 16; n++) wc[n] = w[n*512 + d];
    float bv = bias[d];
    #pragma unroll
    for (int tt = 0; tt < 8; tt++){
      float acc = bv;
      #pragma unroll
      for (int n = 0; n < 16; n++) acc += row[tt][n] * wc[n];
      float sp = (acc > 20.f) ? acc : log1pf(__expf(acc));
      dt[(size_t)(t0+tt)*512 + d] = sp;
    }
  }
}

// ---------------- selective scan: LDS-staged, double-buffered chunks -------
#define SCT 32
#define NCH ((SEQL + SCT - 1)/SCT)   // 7
__global__ __launch_bounds__(256) void scan_kernel(
    const float* __restrict__ dt, const float* __restrict__ u, const float* __restrict__ dbc,
    const float* __restrict__ xz, const float* __restrict__ A_log, const float* __restrict__ Dp,
    __bf16* __restrict__ yg_bf)
{
  __shared__ float s_dt[2][SCT][16];
  __shared__ float s_u [2][SCT][16];
  __shared__ float s_z [2][SCT][16];
  __shared__ float s_bc[2][SCT][32];
  __shared__ float s_y [2][SCT][16];

  int tid = threadIdx.x;
  int n = tid & 15, dl = tid >> 4;
  int b = blockIdx.x >> 5, dg = blockIdx.x & 31;
  int d0 = dg * 16;
  int d  = d0 + dl;
  const size_t base = (size_t)b * SEQL;

  float A = -__expf(A_log[d*DS + n]);
  float h = 0.f;
  float dp = Dp[d];

  float r_dt[2], r_u[2], r_z[2], r_bc[4];

  auto load_regs = [&](int c){
    #pragma unroll
    for (int i = 0; i < 2; i++){
      int v = tid + i*256;
      int tg = c*SCT + (v>>4); if (tg > SEQL-1) tg = SEQL-1;
      size_t t = base + tg;
      r_dt[i] = dt[t*512 + d0 + (v&15)];
      r_u [i] = u [t*512 + d0 + (v&15)];
      r_z [i] = xz[t*1024 + 512 + d0 + (v&15)];
    }
    #pragma unroll
    for (int i = 0; i < 4; i++){
      int v = tid + i*256;
      int tg = c*SCT + (v>>5); if (tg > SEQL-1) tg = SEQL-1;
      r_bc[i] = dbc[(base + tg)*48 + 16 + (v&31)];
    }
  };
  auto write_lds = [&](int buf){
    #pragma unroll
    for (int i = 0; i < 2; i++){
      int v = tid + i*256;
      s_dt[buf][v>>4][v&15] = r_dt[i];
      s_u [buf][v>>4][v&15] = r_u[i];
      s_z [buf][v>>4][v&15] = r_z[i];
    }
    #pragma unroll
    for (int i = 0; i < 4; i++){
      int v = tid + i*256;
      s_bc[buf][v>>5][v&31] = r_bc[i];
    }
  };

  load_regs(0);
  write_lds(0);
  __syncthreads();

  for (int c = 0; c < NCH; c++){
    int cur = c & 1;
    if (c + 1 < NCH) load_regs(c+1);

    int steps = SEQL - c*SCT; if (steps > SCT) steps = SCT;
    for (int tl = 0; tl < steps; tl++){
      float dtv = s_dt[cur][tl][dl];
      float uv  = s_u [cur][tl][dl];
      float Bv  = s_bc[cur][tl][n];
      float Cv  = s_bc[cur][tl][16+n];
      h = __expf(dtv * A) * h + (dtv * uv) * Bv;
      float y = h * Cv;
      y += __shfl_xor(y, 1, 64);
      y += __shfl_xor(y, 2, 64);
      y += __shfl_xor(y, 4, 64);
      y += __shfl_xor(y, 8, 64);
      if (n == 0){
        float zv = s_z[cur][tl][dl];
        float sg = 1.f / (1.f + __expf(-zv));
        s_y[cur][tl][dl] = (y + uv*dp) * zv * sg;
      }
    }
    __syncthreads();
    if (c + 1 < NCH) write_lds(1 - cur);
    #pragma unroll
    for (int i = 0; i < 2; i++){
      int v = tid + i*256;
      int tl = v >> 4, tg = c*SCT + tl;
      if (tg < SEQL)
        yg_bf[(base + tg)*512 + d0 + (v&15)] = (__bf16)s_y[cur][tl][v&15];
    }
    __syncthreads();
  }
}

// ---------------- final: resid add (token 0) + LN + head -------------------
__global__ __launch_bounds__(256) void final_head(
    const float* __restrict__ x, const float* __restrict__ resid,
    const float* __restrict__ g, const float* __restrict__ bta,
    const float* __restrict__ head_w, const float* __restrict__ head_b,
    float* __restrict__ out)
{
  __shared__ float xs[256];
  __shared__ float red[8];
  int b = blockIdx.x, tid = threadIdx.x;
  size_t idx = (size_t)b*SEQL*256 + tid;
  float r = x[idx] + resid[idx];
  float s = r, s2 = r*r;
  block_reduce_2(s, s2, red, tid);
  float mu = s * (1.f/256.f);
  float var = s2 * (1.f/256.f) - mu*mu;
  float rr = rsqrtf(var + 1e-5f);
  xs[tid] = (r - mu) * rr * g[tid] + bta[tid];
  __syncthreads();
  for (int j = tid; j < 1000; j += 256){
    float acc = head_b[j];
    #pragma unroll 8
    for (int k = 0; k < 256; k++) acc += xs[k] * head_w[k*1000 + j];
    out[(size_t)b*1000 + j] = acc;
  }
}

// ---------------------------------------------------------------------------
extern "C" void kernel_launch(void* const* d_in, const int* in_sizes, int n_in,
                              void* d_out, int out_size, void* d_ws, size_t ws_size,
                              hipStream_t stream) {
  const float* img   = (const float*)d_in[0];
  const float* ln1g  = (const float*)d_in[1];
  const float* ln1b  = (const float*)d_in[2];
  const float* pe_w  = (const float*)d_in[3];
  const float* pe_b  = (const float*)d_in[4];
  const float* ln2g  = (const float*)d_in[5];
  const float* ln2b  = (const float*)d_in[6];
  const float* pos   = (const float*)d_in[7];
  const float* cls   = (const float*)d_in[8];
  const float* ln_w  = (const float*)d_in[9];
  const float* ln_b  = (const float*)d_in[10];
  const float* in_w  = (const float*)d_in[11];
  const float* conv_w= (const float*)d_in[12];
  const float* conv_b= (const float*)d_in[13];
  const float* xproj = (const float*)d_in[14];
  const float* dtw   = (const float*)d_in[15];
  const float* dtb   = (const float*)d_in[16];
  const float* A_log = (const float*)d_in[17];
  const float* Dp    = (const float*)d_in[18];
  const float* out_w = (const float*)d_in[19];
  const float* nfw   = (const float*)d_in[20];
  const float* nfb   = (const float*)d_in[21];
  const float* head_w= (const float*)d_in[22];
  const float* head_b= (const float*)d_in[23];
  float* out = (float*)d_out;

  float* ws = (float*)d_ws;
  float* x     = ws;  ws += (size_t)TB*DIMM;
  float* resid = ws;  ws += (size_t)TB*DIMM;
  float* xz    = ws;  ws += (size_t)TB*2*DI;
  float* u     = ws;  ws += (size_t)TB*DI;
  float* dbc   = ws;  ws += (size_t)TB*48;
  float* dt    = ws;  ws += (size_t)TB*DI;
  __bf16* xn_bf = (__bf16*)ws;  ws += (size_t)TB*DIMM/2;
  __bf16* yg_bf = (__bf16*)ws;  ws += (size_t)TB*DI/2;
  __bf16* wt_in = (__bf16*)ws;  ws += (size_t)NL*1024*256/2;
  __bf16* wt_out= (__bf16*)ws;  ws += (size_t)NL*256*512/2;
  __bf16* wt_pe = (__bf16*)ws;  ws += (size_t)256*768/2;
  // aliases (lifetimes don't overlap):
  __bf16* xp_bf = (__bf16*)xz;   // 3136*768 bf16 fits in xz (TB*1024 fp32)
  float*  pemb  = dt;            // 3136*256 fp32 fits in dt (TB*512 fp32)

  // ---- weight prep (bf16 transposed copies; every call, graph-safe) ----
  transpose_bf16<<<dim3(1024/32, 256/32, NL), 256, 0, stream>>>(in_w,  wt_in, 256, 1024);
  transpose_bf16<<<dim3( 256/32, 512/32, NL), 256, 0, stream>>>(out_w, wt_out, 512, 256);
  transpose_bf16<<<dim3( 256/32, 768/32,  1), 256, 0, stream>>>(pe_w,  wt_pe, 768, 256);

  // ---- patch embed ----
  patch_ln1<<<NB*196, 256, 0, stream>>>(img, ln1g, ln1b, xp_bf);
  gemm_bf16<64,64><<<dim3(256/64, (3136+63)/64), 256, 0, stream>>>(
      xp_bf, wt_pe, pe_b, pemb, 3136, 256, 768);
  ln2_pos<<<NB*196, 256, 0, stream>>>(pemb, ln2g, ln2b, pos, x);
  cls_pos<<<NB, 256, 0, stream>>>(cls, pos, x);

  for (int i = 0; i < NL; i++){
    add_ln<<<TB, 256, 0, stream>>>(x, resid, xn_bf, ln_w + i*DIMM, ln_b + i*DIMM, i == 0 ? 1 : 0);
    gemm_bf16<64,128><<<dim3(1024/128, (TB+63)/64), 256, 0, stream>>>(
        xn_bf, wt_in + (size_t)i*1024*256, nullptr, xz, TB, 1024, 256);
    conv_silu<<<(TB*DI + 255)/256, 256, 0, stream>>>(xz, conv_w + i*DI*4, conv_b + i*DI, u);
    gemm_t<64,16,32,4,1><<<dim3(3, (TB+63)/64), 256, 0, stream>>>(
        u, xproj + i*DI*48, nullptr, dbc, TB, 48, DI);
    dtproj_softplus<<<TB/8, 256, 0, stream>>>(dbc, dtw + i*16*DI, dtb + i*DI, dt);
    scan_kernel<<<NB*32, 256, 0, stream>>>(dt, u, dbc, xz, A_log + i*DI*DS, Dp + i*DI, yg_bf);
    gemm_bf16<64,64><<<dim3(DIMM/64, (TB+63)/64), 256, 0, stream>>>(
        yg_bf, wt_out + (size_t)i*256*512, nullptr, x, TB, DIMM, 512);
  }
  final_head<<<NB, 256, 0, stream>>>(x, resid, nfw, nfb, head_w, head_b, out);
}

// Round 5
// 1033.205 us; speedup vs baseline: 4.2995x; 1.2134x over previous
//
#include <hip/hip_runtime.h>
#include <math.h>

#define NB   16      // batch
#define SEQL 197     // sequence length (196 patches + cls)
#define TB   (NB*SEQL)   // 3152 tokens
#define DIMM 256
#define DI   512
#define DS   16
#define NL   8

typedef __bf16 bf16x8 __attribute__((ext_vector_type(8)));
typedef __bf16 bf16x4 __attribute__((ext_vector_type(4)));
typedef float floatx4 __attribute__((ext_vector_type(4)));

// ---------------- block-wide 2-value reduction (256 threads = 4 waves) -----
__device__ __forceinline__ void block_reduce_2(float& s1, float& s2, float* red, int tid){
  #pragma unroll
  for (int off = 32; off > 0; off >>= 1){
    s1 += __shfl_down(s1, off, 64);
    s2 += __shfl_down(s2, off, 64);
  }
  __syncthreads();
  if ((tid & 63) == 0){ red[(tid>>6)*2] = s1; red[(tid>>6)*2+1] = s2; }
  __syncthreads();
  s1 = red[0] + red[2] + red[4] + red[6];
  s2 = red[1] + red[3] + red[5] + red[7];
}

// ---------------- weight cast+transpose: in[K][N] fp32 -> out[N][K] bf16 ---
__global__ __launch_bounds__(256) void transpose_bf16(
    const float* __restrict__ in, __bf16* __restrict__ out, int K, int N)
{
  __shared__ float t[32][33];
  const float* src = in  + (size_t)blockIdx.z*K*N;
  __bf16*      dst = out + (size_t)blockIdx.z*K*N;
  int n0 = blockIdx.x*32, k0 = blockIdx.y*32;
  int tx = threadIdx.x & 31, ty = threadIdx.x >> 5;   // 32 x 8
  #pragma unroll
  for (int j = 0; j < 4; j++)
    t[ty + j*8][tx] = src[(size_t)(k0 + ty + j*8)*N + n0 + tx];
  __syncthreads();
  #pragma unroll
  for (int j = 0; j < 4; j++)
    dst[(size_t)(n0 + ty + j*8)*K + k0 + tx] = (__bf16)t[tx][ty + j*8];
}

// in[K][Nin] fp32 -> out[Npad][K] bf16, rows >= Nin zeroed
__global__ __launch_bounds__(256) void transpose_bf16_pad(
    const float* __restrict__ in, __bf16* __restrict__ out, int K, int Nin, int Npad)
{
  __shared__ float t[32][33];
  const float* src = in  + (size_t)blockIdx.z*K*Nin;
  __bf16*      dst = out + (size_t)blockIdx.z*Npad*K;
  int n0 = blockIdx.x*32, k0 = blockIdx.y*32;
  int tx = threadIdx.x & 31, ty = threadIdx.x >> 5;
  #pragma unroll
  for (int j = 0; j < 4; j++){
    int n = n0 + tx;
    t[ty + j*8][tx] = (n < Nin) ? src[(size_t)(k0 + ty + j*8)*Nin + n] : 0.f;
  }
  __syncthreads();
  #pragma unroll
  for (int j = 0; j < 4; j++)
    dst[(size_t)(n0 + ty + j*8)*K + k0 + tx] = (__bf16)t[tx][ty + j*8];
}

// ---------------- bf16 MFMA GEMM: C fp32 = A[M][K] @ Wt[N][K]^T (+bias) ----
template<int BM, int BN>
__global__ __launch_bounds__(256) void gemm_bf16(
    const __bf16* __restrict__ A, const __bf16* __restrict__ Wt,
    const float* __restrict__ bias, float* __restrict__ C, int M, int N, int K)
{
  constexpr int BK  = 32;
  constexpr int LDA = BK + 8;
  constexpr int TMW = BM/32;
  constexpr int TNW = BN/32;
  __shared__ __bf16 As[BM][LDA];
  __shared__ __bf16 Bs[BN][LDA];

  int tid  = threadIdx.x;
  int lane = tid & 63, w = tid >> 6;
  int wm = w >> 1, wn = w & 1;
  int l15 = lane & 15, quad = lane >> 4;
  int bm = blockIdx.y * BM, bn = blockIdx.x * BN;

  floatx4 acc[TMW][TNW] = {};

  for (int k0 = 0; k0 < K; k0 += BK){
    #pragma unroll
    for (int i = 0; i < BM/64; i++){
      int c = tid + i*256;
      int row = c >> 2, kc = c & 3;
      int m = bm + row;
      uint4 v = make_uint4(0,0,0,0);
      if (m < M) v = ((const uint4*)(A + (size_t)m*K + k0))[kc];
      *(uint4*)&As[row][kc*8] = v;
    }
    #pragma unroll
    for (int i = 0; i < BN/64; i++){
      int c = tid + i*256;
      int row = c >> 2, kc = c & 3;
      int n = bn + row;
      uint4 v = ((const uint4*)(Wt + (size_t)n*K + k0))[kc];
      *(uint4*)&Bs[row][kc*8] = v;
    }
    __syncthreads();
    bf16x8 af[TMW], bf[TNW];
    #pragma unroll
    for (int mi = 0; mi < TMW; mi++)
      af[mi] = *(const bf16x8*)&As[wm*(BM/2) + mi*16 + l15][quad*8];
    #pragma unroll
    for (int ni = 0; ni < TNW; ni++)
      bf[ni] = *(const bf16x8*)&Bs[wn*(BN/2) + ni*16 + l15][quad*8];
    #pragma unroll
    for (int mi = 0; mi < TMW; mi++)
      #pragma unroll
      for (int ni = 0; ni < TNW; ni++)
        acc[mi][ni] = __builtin_amdgcn_mfma_f32_16x16x32_bf16(af[mi], bf[ni], acc[mi][ni], 0, 0, 0);
    __syncthreads();
  }
  #pragma unroll
  for (int mi = 0; mi < TMW; mi++){
    #pragma unroll
    for (int ni = 0; ni < TNW; ni++){
      int col = bn + wn*(BN/2) + ni*16 + l15;
      float bv = bias ? bias[col] : 0.f;
      #pragma unroll
      for (int r = 0; r < 4; r++){
        int row = bm + wm*(BM/2) + mi*16 + quad*4 + r;
        if (row < M) C[(size_t)row*N + col] = acc[mi][ni][r] + bv;
      }
    }
  }
}

// ---------------- patch LN1: gather + LayerNorm(768) -> bf16 ---------------
__global__ __launch_bounds__(256) void patch_ln1(
    const float* __restrict__ img, const float* __restrict__ g1, const float* __restrict__ b1,
    __bf16* __restrict__ xp_bf)
{
  __shared__ float red[8];
  int blk = blockIdx.x;            // b*196 + patch
  int b = blk / 196, p = blk % 196;
  int hh = p / 14, ww = p % 14;
  int tid = threadIdx.x;

  float v[3]; float s = 0.f, s2 = 0.f;
  #pragma unroll
  for (int i = 0; i < 3; i++){
    int e  = tid + i*256;
    int c  = e % 3;
    int p2 = (e/3) % 16;
    int p1 = e / 48;
    float val = img[((b*3 + c)*224 + hh*16 + p1)*224 + ww*16 + p2];
    v[i] = val; s += val; s2 += val*val;
  }
  block_reduce_2(s, s2, red, tid);
  float mu = s * (1.f/768.f);
  float var = s2 * (1.f/768.f) - mu*mu;
  float rr = rsqrtf(var + 1e-5f);
  #pragma unroll
  for (int i = 0; i < 3; i++){
    int e = tid + i*256;
    xp_bf[(size_t)blk*768 + e] = (__bf16)((v[i] - mu) * rr * g1[e] + b1[e]);
  }
}

// ---------------- patch LN2 + pos ------------------------------------------
__global__ __launch_bounds__(256) void ln2_pos(
    const float* __restrict__ pemb, const float* __restrict__ g2, const float* __restrict__ b2,
    const float* __restrict__ pos, float* __restrict__ x)
{
  __shared__ float red[8];
  int blk = blockIdx.x;
  int b = blk / 196, p = blk % 196;
  int tid = threadIdx.x;
  float v = pemb[(size_t)blk*256 + tid];
  float s = v, s2 = v*v;
  block_reduce_2(s, s2, red, tid);
  float mu = s * (1.f/256.f);
  float var = s2 * (1.f/256.f) - mu*mu;
  float rr = rsqrtf(var + 1e-5f);
  float o = (v - mu) * rr * g2[tid] + b2[tid] + pos[(1+p)*256 + tid];
  x[((size_t)(b*SEQL + 1 + p))*256 + tid] = o;
}

// ---------------- cls token + pos[0] ---------------------------------------
__global__ __launch_bounds__(256) void cls_pos(
    const float* __restrict__ cls, const float* __restrict__ pos, float* __restrict__ x)
{
  int b = blockIdx.x, tid = threadIdx.x;
  x[(size_t)b*SEQL*256 + tid] = cls[tid] + pos[tid];
}

// ---------------- residual add + LayerNorm(256) -> bf16, wave-per-token ----
__global__ __launch_bounds__(256) void add_ln(
    const float* __restrict__ x, float* __restrict__ resid, __bf16* __restrict__ xn_bf,
    const float* __restrict__ g, const float* __restrict__ bta, int first)
{
  int w = threadIdx.x >> 6, l = threadIdx.x & 63;
  int t = blockIdx.x*4 + w;
  size_t base = (size_t)t*256 + l*4;
  float4 xv = *(const float4*)&x[base];
  if (!first){
    float4 rv = *(const float4*)&resid[base];
    xv.x += rv.x; xv.y += rv.y; xv.z += rv.z; xv.w += rv.w;
  }
  *(float4*)&resid[base] = xv;
  float s  = xv.x + xv.y + xv.z + xv.w;
  float s2 = xv.x*xv.x + xv.y*xv.y + xv.z*xv.z + xv.w*xv.w;
  #pragma unroll
  for (int off = 1; off < 64; off <<= 1){
    s  += __shfl_xor(s,  off, 64);
    s2 += __shfl_xor(s2, off, 64);
  }
  float mu = s * (1.f/256.f);
  float var = s2 * (1.f/256.f) - mu*mu;
  float rr = rsqrtf(var + 1e-5f);
  float4 gv = *(const float4*)&g[l*4];
  float4 bv = *(const float4*)&bta[l*4];
  bf16x4 o;
  o[0] = (__bf16)((xv.x - mu)*rr*gv.x + bv.x);
  o[1] = (__bf16)((xv.y - mu)*rr*gv.y + bv.y);
  o[2] = (__bf16)((xv.z - mu)*rr*gv.z + bv.z);
  o[3] = (__bf16)((xv.w - mu)*rr*gv.w + bv.w);
  *(bf16x4*)&xn_bf[base] = o;
}

// ---------------- causal depthwise conv (k=4) + SiLU -> fp32 + bf16 --------
__global__ __launch_bounds__(256) void conv_silu(
    const float* __restrict__ xz, const float* __restrict__ cw, const float* __restrict__ cb,
    float* __restrict__ u, __bf16* __restrict__ u_bf)
{
  int gid = blockIdx.x*256 + threadIdx.x;
  if (gid >= TB*DI) return;
  int d = gid & 511;
  int t = gid >> 9;
  int l = t % SEQL;
  float acc = cb[d];
  if (l >= 3) acc += xz[(size_t)(t-3)*1024 + d] * cw[d*4+0];
  if (l >= 2) acc += xz[(size_t)(t-2)*1024 + d] * cw[d*4+1];
  if (l >= 1) acc += xz[(size_t)(t-1)*1024 + d] * cw[d*4+2];
  acc += xz[(size_t)t*1024 + d] * cw[d*4+3];
  float sg = 1.f / (1.f + __expf(-acc));
  float val = acc * sg;
  u[(size_t)t*512 + d] = val;
  u_bf[(size_t)t*512 + d] = (__bf16)val;
}

// ---------------- selective scan + fused dtproj/softplus -------------------
// dbc is [TB][64]: cols 0:16 dt_in, 16:32 B, 32:48 C (48:64 zero).
#define SCT 32
#define NCH ((SEQL + SCT - 1)/SCT)   // 7
__global__ __launch_bounds__(256) void scan_kernel(
    const float* __restrict__ u, const float* __restrict__ dbc,
    const float* __restrict__ xz, const float* __restrict__ A_log, const float* __restrict__ Dp,
    const float* __restrict__ dtw, const float* __restrict__ dtb,
    __bf16* __restrict__ yg_bf)
{
  __shared__ float s_db[2][SCT][48];
  __shared__ float s_u [2][SCT][16];
  __shared__ float s_z [2][SCT][16];
  __shared__ float s_dt[2][SCT][16];
  __shared__ float s_y [2][SCT][16];

  int tid = threadIdx.x;
  int n = tid & 15, dl = tid >> 4;
  int b = blockIdx.x >> 5, dg = blockIdx.x & 31;
  int d0 = dg * 16;
  int d  = d0 + dl;
  const size_t base = (size_t)b * SEQL;

  float A = -__expf(A_log[d*DS + n]);
  float h = 0.f;
  float dp = Dp[d];
  // dtproj weights for output channel d0+n (each thread owns one column)
  float wc[16];
  #pragma unroll
  for (int k = 0; k < 16; k++) wc[k] = dtw[k*512 + d0 + n];
  float dtbv = dtb[d0 + n];

  float r_u[2], r_z[2], r_db[6];

  auto load_regs = [&](int c){
    #pragma unroll
    for (int i = 0; i < 2; i++){
      int v = tid + i*256;
      int tg = c*SCT + (v>>4); if (tg > SEQL-1) tg = SEQL-1;
      size_t t = base + tg;
      r_u[i] = u [t*512 + d0 + (v&15)];
      r_z[i] = xz[t*1024 + 512 + d0 + (v&15)];
    }
    #pragma unroll
    for (int s = 0; s < 3; s++)
      #pragma unroll
      for (int i = 0; i < 2; i++){
        int v = tid + i*256;
        int tg = c*SCT + (v>>4); if (tg > SEQL-1) tg = SEQL-1;
        r_db[s*2+i] = dbc[(base + tg)*64 + s*16 + (v&15)];
      }
  };
  auto write_lds = [&](int buf){
    #pragma unroll
    for (int i = 0; i < 2; i++){
      int v = tid + i*256;
      s_u[buf][v>>4][v&15] = r_u[i];
      s_z[buf][v>>4][v&15] = r_z[i];
    }
    #pragma unroll
    for (int s = 0; s < 3; s++)
      #pragma unroll
      for (int i = 0; i < 2; i++){
        int v = tid + i*256;
        s_db[buf][v>>4][s*16 + (v&15)] = r_db[s*2+i];
      }
  };
  auto compute_dt = [&](int buf){
    #pragma unroll
    for (int i = 0; i < 2; i++){
      int tl = (tid + i*256) >> 4;
      float acc = dtbv;
      #pragma unroll
      for (int k = 0; k < 16; k++) acc += s_db[buf][tl][k] * wc[k];
      s_dt[buf][tl][n] = (acc > 20.f) ? acc : log1pf(__expf(acc));
    }
  };

  load_regs(0);
  write_lds(0);
  __syncthreads();
  compute_dt(0);
  __syncthreads();

  for (int c = 0; c < NCH; c++){
    int cur = c & 1;
    if (c + 1 < NCH) load_regs(c+1);

    int steps = SEQL - c*SCT; if (steps > SCT) steps = SCT;
    for (int tl = 0; tl < steps; tl++){
      float dtv = s_dt[cur][tl][dl];
      float uv  = s_u [cur][tl][dl];
      float Bv  = s_db[cur][tl][16+n];
      float Cv  = s_db[cur][tl][32+n];
      h = __expf(dtv * A) * h + (dtv * uv) * Bv;
      float y = h * Cv;
      y += __shfl_xor(y, 1, 64);
      y += __shfl_xor(y, 2, 64);
      y += __shfl_xor(y, 4, 64);
      y += __shfl_xor(y, 8, 64);
      if (n == 0){
        float zv = s_z[cur][tl][dl];
        float sg = 1.f / (1.f + __expf(-zv));
        s_y[cur][tl][dl] = (y + uv*dp) * zv * sg;
      }
    }
    __syncthreads();
    if (c + 1 < NCH) write_lds(1 - cur);
    #pragma unroll
    for (int i = 0; i < 2; i++){
      int v = tid + i*256;
      int tl = v >> 4, tg = c*SCT + tl;
      if (tg < SEQL)
        yg_bf[(base + tg)*512 + d0 + (v&15)] = (__bf16)s_y[cur][tl][v&15];
    }
    __syncthreads();
    if (c + 1 < NCH){
      compute_dt(1 - cur);
      __syncthreads();
    }
  }
}

// ---------------- final LN (token 0) ---------------------------------------
__global__ __launch_bounds__(256) void final_ln(
    const float* __restrict__ x, const float* __restrict__ resid,
    const float* __restrict__ g, const float* __restrict__ bta, float* __restrict__ xs_g)
{
  __shared__ float red[8];
  int b = blockIdx.x, tid = threadIdx.x;
  size_t idx = (size_t)b*SEQL*256 + tid;
  float r = x[idx] + resid[idx];
  float s = r, s2 = r*r;
  block_reduce_2(s, s2, red, tid);
  float mu = s * (1.f/256.f);
  float var = s2 * (1.f/256.f) - mu*mu;
  float rr = rsqrtf(var + 1e-5f);
  xs_g[b*256 + tid] = (r - mu) * rr * g[tid] + bta[tid];
}

// ---------------- head: out[16][1000] = xs[16][256] @ head_w + head_b ------
__global__ __launch_bounds__(256) void head_gemm(
    const float* __restrict__ xs_g, const float* __restrict__ head_w,
    const float* __restrict__ head_b, float* __restrict__ out)
{
  __shared__ float xs[16][256];
  int tid = threadIdx.x;
  #pragma unroll
  for (int i = 0; i < 16; i++) ((float*)xs)[tid + i*256] = xs_g[tid + i*256];
  __syncthreads();
  int nl = tid & 31, bq = tid >> 5;
  int nn = blockIdx.x*32 + nl;
  if (nn >= 1000) return;
  float acc0 = 0.f, acc1 = 0.f;
  #pragma unroll 8
  for (int k = 0; k < 256; k++){
    float w = head_w[k*1000 + nn];
    acc0 += xs[bq][k]   * w;
    acc1 += xs[bq+8][k] * w;
  }
  float hb = head_b[nn];
  out[(size_t)bq*1000 + nn]     = acc0 + hb;
  out[(size_t)(bq+8)*1000 + nn] = acc1 + hb;
}

// ---------------------------------------------------------------------------
extern "C" void kernel_launch(void* const* d_in, const int* in_sizes, int n_in,
                              void* d_out, int out_size, void* d_ws, size_t ws_size,
                              hipStream_t stream) {
  const float* img   = (const float*)d_in[0];
  const float* ln1g  = (const float*)d_in[1];
  const float* ln1b  = (const float*)d_in[2];
  const float* pe_w  = (const float*)d_in[3];
  const float* pe_b  = (const float*)d_in[4];
  const float* ln2g  = (const float*)d_in[5];
  const float* ln2b  = (const float*)d_in[6];
  const float* pos   = (const float*)d_in[7];
  const float* cls   = (const float*)d_in[8];
  const float* ln_w  = (const float*)d_in[9];
  const float* ln_b  = (const float*)d_in[10];
  const float* in_w  = (const float*)d_in[11];
  const float* conv_w= (const float*)d_in[12];
  const float* conv_b= (const float*)d_in[13];
  const float* xproj = (const float*)d_in[14];
  const float* dtw   = (const float*)d_in[15];
  const float* dtb   = (const float*)d_in[16];
  const float* A_log = (const float*)d_in[17];
  const float* Dp    = (const float*)d_in[18];
  const float* out_w = (const float*)d_in[19];
  const float* nfw   = (const float*)d_in[20];
  const float* nfb   = (const float*)d_in[21];
  const float* head_w= (const float*)d_in[22];
  const float* head_b= (const float*)d_in[23];
  float* out = (float*)d_out;

  float* ws = (float*)d_ws;
  float* x     = ws;  ws += (size_t)TB*DIMM;
  float* resid = ws;  ws += (size_t)TB*DIMM;
  float* xz    = ws;  ws += (size_t)TB*2*DI;
  float* u     = ws;  ws += (size_t)TB*DI;
  float* dbc   = ws;  ws += (size_t)TB*64;      // padded N=64 layout
  float* xs_g  = ws;  ws += (size_t)NB*DIMM;
  __bf16* xn_bf = (__bf16*)ws;  ws += (size_t)TB*DIMM/2;
  __bf16* u_bf  = (__bf16*)ws;  ws += (size_t)TB*DI/2;
  __bf16* yg_bf = (__bf16*)ws;  ws += (size_t)TB*DI/2;
  __bf16* wt_in = (__bf16*)ws;  ws += (size_t)NL*1024*256/2;
  __bf16* wt_out= (__bf16*)ws;  ws += (size_t)NL*256*512/2;
  __bf16* wt_pe = (__bf16*)ws;  ws += (size_t)256*768/2;
  __bf16* wt_xp = (__bf16*)ws;  ws += (size_t)NL*64*512/2;
  // aliases (lifetimes don't overlap):
  __bf16* xp_bf = (__bf16*)xz;   // 3136*768 bf16 fits in xz
  float*  pemb  = u;             // 3136*256 fp32 fits in u

  // ---- weight prep (bf16 transposed copies; every call, graph-safe) ----
  transpose_bf16<<<dim3(1024/32, 256/32, NL), 256, 0, stream>>>(in_w,  wt_in, 256, 1024);
  transpose_bf16<<<dim3( 256/32, 512/32, NL), 256, 0, stream>>>(out_w, wt_out, 512, 256);
  transpose_bf16<<<dim3( 256/32, 768/32,  1), 256, 0, stream>>>(pe_w,  wt_pe, 768, 256);
  transpose_bf16_pad<<<dim3(2, 512/32, NL), 256, 0, stream>>>(xproj, wt_xp, 512, 48, 64);

  // ---- patch embed ----
  patch_ln1<<<NB*196, 256, 0, stream>>>(img, ln1g, ln1b, xp_bf);
  gemm_bf16<64,64><<<dim3(256/64, 3136/64), 256, 0, stream>>>(
      xp_bf, wt_pe, pe_b, pemb, 3136, 256, 768);
  ln2_pos<<<NB*196, 256, 0, stream>>>(pemb, ln2g, ln2b, pos, x);
  cls_pos<<<NB, 256, 0, stream>>>(cls, pos, x);

  for (int i = 0; i < NL; i++){
    add_ln<<<TB/4, 256, 0, stream>>>(x, resid, xn_bf, ln_w + i*DIMM, ln_b + i*DIMM, i == 0 ? 1 : 0);
    gemm_bf16<64,128><<<dim3(1024/128, (TB+63)/64), 256, 0, stream>>>(
        xn_bf, wt_in + (size_t)i*1024*256, nullptr, xz, TB, 1024, 256);
    conv_silu<<<(TB*DI + 255)/256, 256, 0, stream>>>(xz, conv_w + i*DI*4, conv_b + i*DI, u, u_bf);
    gemm_bf16<64,64><<<dim3(1, (TB+63)/64), 256, 0, stream>>>(
        u_bf, wt_xp + (size_t)i*64*512, nullptr, dbc, TB, 64, 512);
    scan_kernel<<<NB*32, 256, 0, stream>>>(
        u, dbc, xz, A_log + i*DI*DS, Dp + i*DI, dtw + i*16*DI, dtb + i*DI, yg_bf);
    gemm_bf16<64,64><<<dim3(DIMM/64, (TB+63)/64), 256, 0, stream>>>(
        yg_bf, wt_out + (size_t)i*256*512, nullptr, x, TB, DIMM, 512);
  }
  final_ln<<<NB, 256, 0, stream>>>(x, resid, nfw, nfb, xs_g);
  head_gemm<<<(1000+31)/32, 256, 0, stream>>>(xs_g, head_w, head_b, out);
}

// Round 6
// 725.311 us; speedup vs baseline: 6.1246x; 1.4245x over previous
//
#include <hip/hip_runtime.h>
#include <math.h>

#define NB   16      // batch
#define SEQL 197     // sequence length (196 patches + cls)
#define TB   (NB*SEQL)   // 3152 tokens
#define DIMM 256
#define DI   512
#define DS   16
#define NL   8

typedef __bf16 bf16x8 __attribute__((ext_vector_type(8)));
typedef __bf16 bf16x4 __attribute__((ext_vector_type(4)));
typedef float floatx4 __attribute__((ext_vector_type(4)));

// ---------------- block-wide 2-value reduction (256 threads = 4 waves) -----
__device__ __forceinline__ void block_reduce_2(float& s1, float& s2, float* red, int tid){
  #pragma unroll
  for (int off = 32; off > 0; off >>= 1){
    s1 += __shfl_down(s1, off, 64);
    s2 += __shfl_down(s2, off, 64);
  }
  __syncthreads();
  if ((tid & 63) == 0){ red[(tid>>6)*2] = s1; red[(tid>>6)*2+1] = s2; }
  __syncthreads();
  s1 = red[0] + red[2] + red[4] + red[6];
  s2 = red[1] + red[3] + red[5] + red[7];
}

// ---------------- weight cast+transpose: in[K][N] fp32 -> out[N][K] bf16 ---
__global__ __launch_bounds__(256) void transpose_bf16(
    const float* __restrict__ in, __bf16* __restrict__ out, int K, int N)
{
  __shared__ float t[32][33];
  const float* src = in  + (size_t)blockIdx.z*K*N;
  __bf16*      dst = out + (size_t)blockIdx.z*K*N;
  int n0 = blockIdx.x*32, k0 = blockIdx.y*32;
  int tx = threadIdx.x & 31, ty = threadIdx.x >> 5;   // 32 x 8
  #pragma unroll
  for (int j = 0; j < 4; j++)
    t[ty + j*8][tx] = src[(size_t)(k0 + ty + j*8)*N + n0 + tx];
  __syncthreads();
  #pragma unroll
  for (int j = 0; j < 4; j++)
    dst[(size_t)(n0 + ty + j*8)*K + k0 + tx] = (__bf16)t[tx][ty + j*8];
}

// in[K][Nin] fp32 -> out[Npad][K] bf16, rows >= Nin zeroed
__global__ __launch_bounds__(256) void transpose_bf16_pad(
    const float* __restrict__ in, __bf16* __restrict__ out, int K, int Nin, int Npad)
{
  __shared__ float t[32][33];
  const float* src = in  + (size_t)blockIdx.z*K*Nin;
  __bf16*      dst = out + (size_t)blockIdx.z*Npad*K;
  int n0 = blockIdx.x*32, k0 = blockIdx.y*32;
  int tx = threadIdx.x & 31, ty = threadIdx.x >> 5;
  #pragma unroll
  for (int j = 0; j < 4; j++){
    int n = n0 + tx;
    t[ty + j*8][tx] = (n < Nin) ? src[(size_t)(k0 + ty + j*8)*Nin + n] : 0.f;
  }
  __syncthreads();
  #pragma unroll
  for (int j = 0; j < 4; j++)
    dst[(size_t)(n0 + ty + j*8)*K + k0 + tx] = (__bf16)t[tx][ty + j*8];
}

// ---------------- bf16 MFMA GEMM: C fp32 = A[M][K] @ Wt[N][K]^T (+bias) ----
template<int BM, int BN>
__global__ __launch_bounds__(256) void gemm_bf16(
    const __bf16* __restrict__ A, const __bf16* __restrict__ Wt,
    const float* __restrict__ bias, float* __restrict__ C, int M, int N, int K)
{
  constexpr int BK  = 32;
  constexpr int LDA = BK + 8;
  constexpr int TMW = BM/32;
  constexpr int TNW = BN/32;
  __shared__ __bf16 As[BM][LDA];
  __shared__ __bf16 Bs[BN][LDA];

  int tid  = threadIdx.x;
  int lane = tid & 63, w = tid >> 6;
  int wm = w >> 1, wn = w & 1;
  int l15 = lane & 15, quad = lane >> 4;
  int bm = blockIdx.y * BM, bn = blockIdx.x * BN;

  floatx4 acc[TMW][TNW] = {};

  for (int k0 = 0; k0 < K; k0 += BK){
    #pragma unroll
    for (int i = 0; i < BM/64; i++){
      int c = tid + i*256;
      int row = c >> 2, kc = c & 3;
      int m = bm + row;
      uint4 v = make_uint4(0,0,0,0);
      if (m < M) v = ((const uint4*)(A + (size_t)m*K + k0))[kc];
      *(uint4*)&As[row][kc*8] = v;
    }
    #pragma unroll
    for (int i = 0; i < BN/64; i++){
      int c = tid + i*256;
      int row = c >> 2, kc = c & 3;
      int n = bn + row;
      uint4 v = ((const uint4*)(Wt + (size_t)n*K + k0))[kc];
      *(uint4*)&Bs[row][kc*8] = v;
    }
    __syncthreads();
    bf16x8 af[TMW], bf[TNW];
    #pragma unroll
    for (int mi = 0; mi < TMW; mi++)
      af[mi] = *(const bf16x8*)&As[wm*(BM/2) + mi*16 + l15][quad*8];
    #pragma unroll
    for (int ni = 0; ni < TNW; ni++)
      bf[ni] = *(const bf16x8*)&Bs[wn*(BN/2) + ni*16 + l15][quad*8];
    #pragma unroll
    for (int mi = 0; mi < TMW; mi++)
      #pragma unroll
      for (int ni = 0; ni < TNW; ni++)
        acc[mi][ni] = __builtin_amdgcn_mfma_f32_16x16x32_bf16(af[mi], bf[ni], acc[mi][ni], 0, 0, 0);
    __syncthreads();
  }
  #pragma unroll
  for (int mi = 0; mi < TMW; mi++){
    #pragma unroll
    for (int ni = 0; ni < TNW; ni++){
      int col = bn + wn*(BN/2) + ni*16 + l15;
      float bv = bias ? bias[col] : 0.f;
      #pragma unroll
      for (int r = 0; r < 4; r++){
        int row = bm + wm*(BM/2) + mi*16 + quad*4 + r;
        if (row < M) C[(size_t)row*N + col] = acc[mi][ni][r] + bv;
      }
    }
  }
}

// ---------------- patch LN1: gather + LayerNorm(768) -> bf16 ---------------
__global__ __launch_bounds__(256) void patch_ln1(
    const float* __restrict__ img, const float* __restrict__ g1, const float* __restrict__ b1,
    __bf16* __restrict__ xp_bf)
{
  __shared__ float red[8];
  int blk = blockIdx.x;            // b*196 + patch
  int b = blk / 196, p = blk % 196;
  int hh = p / 14, ww = p % 14;
  int tid = threadIdx.x;

  float v[3]; float s = 0.f, s2 = 0.f;
  #pragma unroll
  for (int i = 0; i < 3; i++){
    int e  = tid + i*256;
    int c  = e % 3;
    int p2 = (e/3) % 16;
    int p1 = e / 48;
    float val = img[((b*3 + c)*224 + hh*16 + p1)*224 + ww*16 + p2];
    v[i] = val; s += val; s2 += val*val;
  }
  block_reduce_2(s, s2, red, tid);
  float mu = s * (1.f/768.f);
  float var = s2 * (1.f/768.f) - mu*mu;
  float rr = rsqrtf(var + 1e-5f);
  #pragma unroll
  for (int i = 0; i < 3; i++){
    int e = tid + i*256;
    xp_bf[(size_t)blk*768 + e] = (__bf16)((v[i] - mu) * rr * g1[e] + b1[e]);
  }
}

// ---------------- patch LN2 + pos ------------------------------------------
__global__ __launch_bounds__(256) void ln2_pos(
    const float* __restrict__ pemb, const float* __restrict__ g2, const float* __restrict__ b2,
    const float* __restrict__ pos, float* __restrict__ x)
{
  __shared__ float red[8];
  int blk = blockIdx.x;
  int b = blk / 196, p = blk % 196;
  int tid = threadIdx.x;
  float v = pemb[(size_t)blk*256 + tid];
  float s = v, s2 = v*v;
  block_reduce_2(s, s2, red, tid);
  float mu = s * (1.f/256.f);
  float var = s2 * (1.f/256.f) - mu*mu;
  float rr = rsqrtf(var + 1e-5f);
  float o = (v - mu) * rr * g2[tid] + b2[tid] + pos[(1+p)*256 + tid];
  x[((size_t)(b*SEQL + 1 + p))*256 + tid] = o;
}

// ---------------- cls token + pos[0] ---------------------------------------
__global__ __launch_bounds__(256) void cls_pos(
    const float* __restrict__ cls, const float* __restrict__ pos, float* __restrict__ x)
{
  int b = blockIdx.x, tid = threadIdx.x;
  x[(size_t)b*SEQL*256 + tid] = cls[tid] + pos[tid];
}

// ---------------- residual add + LayerNorm(256) -> bf16, wave-per-token ----
__global__ __launch_bounds__(256) void add_ln(
    const float* __restrict__ x, float* __restrict__ resid, __bf16* __restrict__ xn_bf,
    const float* __restrict__ g, const float* __restrict__ bta, int first)
{
  int w = threadIdx.x >> 6, l = threadIdx.x & 63;
  int t = blockIdx.x*4 + w;
  size_t base = (size_t)t*256 + l*4;
  float4 xv = *(const float4*)&x[base];
  if (!first){
    float4 rv = *(const float4*)&resid[base];
    xv.x += rv.x; xv.y += rv.y; xv.z += rv.z; xv.w += rv.w;
  }
  *(float4*)&resid[base] = xv;
  float s  = xv.x + xv.y + xv.z + xv.w;
  float s2 = xv.x*xv.x + xv.y*xv.y + xv.z*xv.z + xv.w*xv.w;
  #pragma unroll
  for (int off = 1; off < 64; off <<= 1){
    s  += __shfl_xor(s,  off, 64);
    s2 += __shfl_xor(s2, off, 64);
  }
  float mu = s * (1.f/256.f);
  float var = s2 * (1.f/256.f) - mu*mu;
  float rr = rsqrtf(var + 1e-5f);
  float4 gv = *(const float4*)&g[l*4];
  float4 bv = *(const float4*)&bta[l*4];
  bf16x4 o;
  o[0] = (__bf16)((xv.x - mu)*rr*gv.x + bv.x);
  o[1] = (__bf16)((xv.y - mu)*rr*gv.y + bv.y);
  o[2] = (__bf16)((xv.z - mu)*rr*gv.z + bv.z);
  o[3] = (__bf16)((xv.w - mu)*rr*gv.w + bv.w);
  *(bf16x4*)&xn_bf[base] = o;
}

// ---------------- causal depthwise conv (k=4) + SiLU -> fp32 + bf16 --------
__global__ __launch_bounds__(256) void conv_silu(
    const float* __restrict__ xz, const float* __restrict__ cw, const float* __restrict__ cb,
    float* __restrict__ u, __bf16* __restrict__ u_bf)
{
  int gid = blockIdx.x*256 + threadIdx.x;
  if (gid >= TB*DI) return;
  int d = gid & 511;
  int t = gid >> 9;
  int l = t % SEQL;
  float acc = cb[d];
  if (l >= 3) acc += xz[(size_t)(t-3)*1024 + d] * cw[d*4+0];
  if (l >= 2) acc += xz[(size_t)(t-2)*1024 + d] * cw[d*4+1];
  if (l >= 1) acc += xz[(size_t)(t-1)*1024 + d] * cw[d*4+2];
  acc += xz[(size_t)t*1024 + d] * cw[d*4+3];
  float sg = 1.f / (1.f + __expf(-acc));
  float val = acc * sg;
  u[(size_t)t*512 + d] = val;
  u_bf[(size_t)t*512 + d] = (__bf16)val;
}

// ---------------- selective scan + fused dtproj/softplus -------------------
// dbc is [TB][64]: cols 0:16 dt_in, 16:32 B, 32:48 C (48:64 zero).
// Block = (b, group of 16 d). tid = dl*16 + n. Hot loop: fully unrolled 32
// steps, no cross-lane ops; per-state partials h*C go to LDS, reduced in a
// separate phase. All staging single-buffered, slotted between the syncs.
#define SCT 32
#define NCH ((SEQL + SCT - 1)/SCT)   // 7
__global__ __launch_bounds__(256) void scan_kernel(
    const float* __restrict__ u, const float* __restrict__ dbc,
    const float* __restrict__ xz, const float* __restrict__ A_log, const float* __restrict__ Dp,
    const float* __restrict__ dtw, const float* __restrict__ dtb,
    __bf16* __restrict__ yg_bf)
{
  __shared__ float s_D [16][36];        // dt_in  [k][tl]
  __shared__ float s_B [16][36];        // B      [n][tl]
  __shared__ float s_C [16][36];        // C      [n][tl]
  __shared__ float s_u [16][36];        // u      [dl][tl]
  __shared__ float s_z [16][36];        // z      [dl][tl]
  __shared__ float s_dt[16][36];        // softplus dt [dl][tl]
  __shared__ float s_yp[SCT][16][20];   // y partials [tl][dl][n] (pad 20: 16B-aligned rows)
  __shared__ float s_dp[16];

  int tid = threadIdx.x;
  int n = tid & 15, dl = tid >> 4;
  int b = blockIdx.x >> 5, dg = blockIdx.x & 31;
  int d0 = dg * 16;
  const size_t base = (size_t)b * SEQL;

  float A = -__expf(A_log[(d0+dl)*DS + n]);
  float h = 0.f;
  if (tid < 16) s_dp[tid] = Dp[d0 + tid];
  float wc[16];
  #pragma unroll
  for (int k = 0; k < 16; k++) wc[k] = dtw[k*512 + d0 + n];
  float dtbv = dtb[d0 + n];

  float r_u[2], r_z[2], r_db[6];
  auto load_regs = [&](int c){
    #pragma unroll
    for (int i = 0; i < 2; i++){
      int v = tid + i*256;
      int tg = c*SCT + (v>>4); if (tg > SEQL-1) tg = SEQL-1;
      size_t t = base + tg;
      r_u[i] = u [t*512 + d0 + (v&15)];
      r_z[i] = xz[t*1024 + 512 + d0 + (v&15)];
    }
    #pragma unroll
    for (int s = 0; s < 3; s++)
      #pragma unroll
      for (int i = 0; i < 2; i++){
        int v = tid + i*256;
        int tg = c*SCT + (v>>4); if (tg > SEQL-1) tg = SEQL-1;
        r_db[s*2+i] = dbc[(base + tg)*64 + s*16 + (v&15)];
      }
  };
  auto write_DBC = [&](){
    #pragma unroll
    for (int i = 0; i < 2; i++){
      int v = tid + i*256;
      s_D[v&15][v>>4] = r_db[0+i];
      s_B[v&15][v>>4] = r_db[2+i];
      s_C[v&15][v>>4] = r_db[4+i];
    }
  };
  auto write_UZ = [&](){
    #pragma unroll
    for (int i = 0; i < 2; i++){
      int v = tid + i*256;
      s_u[v&15][v>>4] = r_u[i];
      s_z[v&15][v>>4] = r_z[i];
    }
  };
  auto compute_dt = [&](){
    #pragma unroll
    for (int i = 0; i < 2; i++){
      int tl = (tid >> 4) + i*16;
      float acc = dtbv;
      #pragma unroll
      for (int k = 0; k < 16; k++) acc += s_D[k][tl] * wc[k];
      s_dt[n][tl] = (acc > 20.f) ? acc : log1pf(__expf(acc));
    }
  };

  // prologue: stage chunk 0
  load_regs(0);
  write_DBC();
  write_UZ();
  __syncthreads();
  compute_dt();
  __syncthreads();

  for (int c = 0; c < NCH; c++){
    if (c + 1 < NCH) load_regs(c+1);        // global loads in flight over compute

    // ---- hot loop: 32 steps, unrolled, no cross-lane deps ----
    float4 dt4, u4, B4, C4;
    #pragma unroll
    for (int tl = 0; tl < SCT; tl++){
      if ((tl & 3) == 0){
        dt4 = *(const float4*)&s_dt[dl][tl];
        u4  = *(const float4*)&s_u [dl][tl];
        B4  = *(const float4*)&s_B [n][tl];
        C4  = *(const float4*)&s_C [n][tl];
      }
      float dtv = ((float*)&dt4)[tl&3];
      float uv  = ((float*)&u4 )[tl&3];
      float Bv  = ((float*)&B4 )[tl&3];
      float Cv  = ((float*)&C4 )[tl&3];
      h = __expf(dtv * A) * h + (dtv * uv) * Bv;
      s_yp[tl][dl][n] = h * Cv;
    }
    __syncthreads();                         // (1) y-partials visible

    if (c + 1 < NCH) write_DBC();            // stage next D/B/C (consumed after sync 2/3)

    // ---- reduction + gate + store ----
    #pragma unroll
    for (int j = 0; j < 2; j++){
      int p = tid + j*256;
      int tl = p >> 4, dr = p & 15;
      float4 a0 = *(const float4*)&s_yp[tl][dr][0];
      float4 a1 = *(const float4*)&s_yp[tl][dr][4];
      float4 a2 = *(const float4*)&s_yp[tl][dr][8];
      float4 a3 = *(const float4*)&s_yp[tl][dr][12];
      float yv = ((a0.x+a0.y)+(a0.z+a0.w)) + ((a1.x+a1.y)+(a1.z+a1.w))
               + ((a2.x+a2.y)+(a2.z+a2.w)) + ((a3.x+a3.y)+(a3.z+a3.w));
      int tg = c*SCT + tl;
      if (tg < SEQL){
        float uv = s_u[dr][tl];
        float zv = s_z[dr][tl];
        float sg = 1.f / (1.f + __expf(-zv));
        yg_bf[(base + tg)*512 + d0 + dr] = (__bf16)((yv + uv*s_dp[dr]) * zv * sg);
      }
    }
    __syncthreads();                         // (2) u/z reads done; s_D complete

    if (c + 1 < NCH){
      write_UZ();                            // stage next u/z
      compute_dt();                          // next dt from s_D
      __syncthreads();                       // (3) s_dt/s_u/s_z ready
    }
  }
}

// ---------------- final LN (token 0) ---------------------------------------
__global__ __launch_bounds__(256) void final_ln(
    const float* __restrict__ x, const float* __restrict__ resid,
    const float* __restrict__ g, const float* __restrict__ bta, float* __restrict__ xs_g)
{
  __shared__ float red[8];
  int b = blockIdx.x, tid = threadIdx.x;
  size_t idx = (size_t)b*SEQL*256 + tid;
  float r = x[idx] + resid[idx];
  float s = r, s2 = r*r;
  block_reduce_2(s, s2, red, tid);
  float mu = s * (1.f/256.f);
  float var = s2 * (1.f/256.f) - mu*mu;
  float rr = rsqrtf(var + 1e-5f);
  xs_g[b*256 + tid] = (r - mu) * rr * g[tid] + bta[tid];
}

// ---------------- head: out[16][1000] = xs[16][256] @ head_w + head_b ------
__global__ __launch_bounds__(256) void head_gemm(
    const float* __restrict__ xs_g, const float* __restrict__ head_w,
    const float* __restrict__ head_b, float* __restrict__ out)
{
  __shared__ float xs[16][256];
  int tid = threadIdx.x;
  #pragma unroll
  for (int i = 0; i < 16; i++) ((float*)xs)[tid + i*256] = xs_g[tid + i*256];
  __syncthreads();
  int nl = tid & 31, bq = tid >> 5;
  int nn = blockIdx.x*32 + nl;
  if (nn >= 1000) return;
  float acc0 = 0.f, acc1 = 0.f;
  #pragma unroll 8
  for (int k = 0; k < 256; k++){
    float w = head_w[k*1000 + nn];
    acc0 += xs[bq][k]   * w;
    acc1 += xs[bq+8][k] * w;
  }
  float hb = head_b[nn];
  out[(size_t)bq*1000 + nn]     = acc0 + hb;
  out[(size_t)(bq+8)*1000 + nn] = acc1 + hb;
}

// ---------------------------------------------------------------------------
extern "C" void kernel_launch(void* const* d_in, const int* in_sizes, int n_in,
                              void* d_out, int out_size, void* d_ws, size_t ws_size,
                              hipStream_t stream) {
  const float* img   = (const float*)d_in[0];
  const float* ln1g  = (const float*)d_in[1];
  const float* ln1b  = (const float*)d_in[2];
  const float* pe_w  = (const float*)d_in[3];
  const float* pe_b  = (const float*)d_in[4];
  const float* ln2g  = (const float*)d_in[5];
  const float* ln2b  = (const float*)d_in[6];
  const float* pos   = (const float*)d_in[7];
  const float* cls   = (const float*)d_in[8];
  const float* ln_w  = (const float*)d_in[9];
  const float* ln_b  = (const float*)d_in[10];
  const float* in_w  = (const float*)d_in[11];
  const float* conv_w= (const float*)d_in[12];
  const float* conv_b= (const float*)d_in[13];
  const float* xproj = (const float*)d_in[14];
  const float* dtw   = (const float*)d_in[15];
  const float* dtb   = (const float*)d_in[16];
  const float* A_log = (const float*)d_in[17];
  const float* Dp    = (const float*)d_in[18];
  const float* out_w = (const float*)d_in[19];
  const float* nfw   = (const float*)d_in[20];
  const float* nfb   = (const float*)d_in[21];
  const float* head_w= (const float*)d_in[22];
  const float* head_b= (const float*)d_in[23];
  float* out = (float*)d_out;

  float* ws = (float*)d_ws;
  float* x     = ws;  ws += (size_t)TB*DIMM;
  float* resid = ws;  ws += (size_t)TB*DIMM;
  float* xz    = ws;  ws += (size_t)TB*2*DI;
  float* u     = ws;  ws += (size_t)TB*DI;
  float* dbc   = ws;  ws += (size_t)TB*64;      // padded N=64 layout
  float* xs_g  = ws;  ws += (size_t)NB*DIMM;
  __bf16* xn_bf = (__bf16*)ws;  ws += (size_t)TB*DIMM/2;
  __bf16* u_bf  = (__bf16*)ws;  ws += (size_t)TB*DI/2;
  __bf16* yg_bf = (__bf16*)ws;  ws += (size_t)TB*DI/2;
  __bf16* wt_in = (__bf16*)ws;  ws += (size_t)NL*1024*256/2;
  __bf16* wt_out= (__bf16*)ws;  ws += (size_t)NL*256*512/2;
  __bf16* wt_pe = (__bf16*)ws;  ws += (size_t)256*768/2;
  __bf16* wt_xp = (__bf16*)ws;  ws += (size_t)NL*64*512/2;
  // aliases (lifetimes don't overlap):
  __bf16* xp_bf = (__bf16*)xz;   // 3136*768 bf16 fits in xz
  float*  pemb  = u;             // 3136*256 fp32 fits in u

  // ---- weight prep (bf16 transposed copies; every call, graph-safe) ----
  transpose_bf16<<<dim3(1024/32, 256/32, NL), 256, 0, stream>>>(in_w,  wt_in, 256, 1024);
  transpose_bf16<<<dim3( 256/32, 512/32, NL), 256, 0, stream>>>(out_w, wt_out, 512, 256);
  transpose_bf16<<<dim3( 256/32, 768/32,  1), 256, 0, stream>>>(pe_w,  wt_pe, 768, 256);
  transpose_bf16_pad<<<dim3(2, 512/32, NL), 256, 0, stream>>>(xproj, wt_xp, 512, 48, 64);

  // ---- patch embed ----
  patch_ln1<<<NB*196, 256, 0, stream>>>(img, ln1g, ln1b, xp_bf);
  gemm_bf16<64,64><<<dim3(256/64, 3136/64), 256, 0, stream>>>(
      xp_bf, wt_pe, pe_b, pemb, 3136, 256, 768);
  ln2_pos<<<NB*196, 256, 0, stream>>>(pemb, ln2g, ln2b, pos, x);
  cls_pos<<<NB, 256, 0, stream>>>(cls, pos, x);

  for (int i = 0; i < NL; i++){
    add_ln<<<TB/4, 256, 0, stream>>>(x, resid, xn_bf, ln_w + i*DIMM, ln_b + i*DIMM, i == 0 ? 1 : 0);
    gemm_bf16<64,128><<<dim3(1024/128, (TB+63)/64), 256, 0, stream>>>(
        xn_bf, wt_in + (size_t)i*1024*256, nullptr, xz, TB, 1024, 256);
    conv_silu<<<(TB*DI + 255)/256, 256, 0, stream>>>(xz, conv_w + i*DI*4, conv_b + i*DI, u, u_bf);
    gemm_bf16<64,64><<<dim3(1, (TB+63)/64), 256, 0, stream>>>(
        u_bf, wt_xp + (size_t)i*64*512, nullptr, dbc, TB, 64, 512);
    scan_kernel<<<NB*32, 256, 0, stream>>>(
        u, dbc, xz, A_log + i*DI*DS, Dp + i*DI, dtw + i*16*DI, dtb + i*DI, yg_bf);
    gemm_bf16<64,64><<<dim3(DIMM/64, (TB+63)/64), 256, 0, stream>>>(
        yg_bf, wt_out + (size_t)i*256*512, nullptr, x, TB, DIMM, 512);
  }
  final_ln<<<NB, 256, 0, stream>>>(x, resid, nfw, nfb, xs_g);
  head_gemm<<<(1000+31)/32, 256, 0, stream>>>(xs_g, head_w, head_b, out);
}